// Round 3
// baseline (746.844 us; speedup 1.0000x reference)
//
#include <hip/hip_runtime.h>
#include <hip/hip_bf16.h>
#include <stdint.h>
#include <math.h>

// Problem constants
#define NB 4
#define NT 2048
#define NC 2048
#define NH 16
#define HD 128
#define BT (NB*NT)   // 8192

typedef __attribute__((ext_vector_type(8))) short s16x8;
typedef __attribute__((ext_vector_type(4))) short s16x4;
typedef __attribute__((ext_vector_type(4))) float f32x4;

typedef __attribute__((address_space(1))) void as1_void;
typedef __attribute__((address_space(3))) void as3_void;

static __device__ __forceinline__ unsigned short f2bf(float f) {
  union { float f; uint32_t u; } v; v.f = f;
  return (unsigned short)((v.u + 0x7fffu + ((v.u >> 16) & 1u)) >> 16);
}
static __device__ __forceinline__ float bf2f(unsigned short u) {
  union { uint32_t u; float f; } v; v.u = ((uint32_t)u) << 16;
  return v.f;
}
static __device__ __forceinline__ void async16(unsigned short* lds, const unsigned short* g) {
  __builtin_amdgcn_global_load_lds((as1_void*)g, (as3_void*)lds, 16, 0, 0);
}
static __device__ __forceinline__ uint32_t lds_off(void* p) {
  return (uint32_t)(size_t)(as3_void*)p;
}

// ---------------- fp32 -> bf16 convert (vectorized, 8 elems/thread) ----------------
__global__ void k_convert_bf16(const float* __restrict__ in, unsigned short* __restrict__ out, int n8) {
  int i = blockIdx.x * blockDim.x + threadIdx.x;
  if (i >= n8) return;
  const float4* p = (const float4*)in + (size_t)i * 2;
  float4 a = p[0], b = p[1];
  union { unsigned short s[8]; uint4 u; } o;
  o.s[0] = f2bf(a.x); o.s[1] = f2bf(a.y); o.s[2] = f2bf(a.z); o.s[3] = f2bf(a.w);
  o.s[4] = f2bf(b.x); o.s[5] = f2bf(b.y); o.s[6] = f2bf(b.z); o.s[7] = f2bf(b.w);
  ((uint4*)out)[i] = o.u;
}

// ---------------- transpose + convert: W [K][N] fp32 -> WT [N][K] bf16 ----------------
__global__ void k_transpose_bf16(const float* __restrict__ W, unsigned short* __restrict__ WT, int K, int N) {
  __shared__ unsigned short tile[64][65];
  const int k0 = blockIdx.y * 64, n0 = blockIdx.x * 64;
  const int t = threadIdx.x;
  const int jj = t & 63, base_i = t >> 6;
  #pragma unroll
  for (int p = 0; p < 16; ++p) {
    int i = p * 4 + base_i;
    tile[i][jj] = f2bf(W[(size_t)(k0 + i) * N + n0 + jj]);
  }
  __syncthreads();
  #pragma unroll
  for (int p = 0; p < 16; ++p) {
    int j = p * 4 + base_i;
    WT[(size_t)(n0 + j) * K + k0 + jj] = tile[jj][j];
  }
}

// ---------------- RoPE in-place on Q,K [BH][T][D]; fold scale*log2e into Q ----------------
__global__ void k_rope(unsigned short* __restrict__ Q, unsigned short* __restrict__ Kb) {
  int idx = blockIdx.x * 256 + threadIdx.x;  // over BH*T*64
  int d = idx & 63;
  int tpos = (idx >> 6) & (NT - 1);
  int bh = idx >> 17;
  size_t o = ((size_t)bh * NT + tpos) * HD + d;
  float invf = exp2f(-(float)d * 0.2076205059304602f);  // log2(10000)/64
  float ang = (float)tpos * invf;
  float s, c;
  sincosf(ang, &s, &c);
  float q1 = bf2f(Q[o]),  q2 = bf2f(Q[o + 64]);
  float k1 = bf2f(Kb[o]), k2 = bf2f(Kb[o + 64]);
  const float qs = 0.08838834764831845f * 1.4426950408889634f;  // (1/sqrt(128))*log2e
  Q[o]       = f2bf((q1 * c - q2 * s) * qs);
  Q[o + 64]  = f2bf((q2 * c + q1 * s) * qs);
  Kb[o]      = f2bf(k1 * c - k2 * s);
  Kb[o + 64] = f2bf(k2 * c + k1 * s);
}

// ---------------- GEMM: C[M][N] = A[M][K] * Bt[N][K]^T + bias ----------------
// MODE 0: scatter bf16 into Q/K/V [B][H][T][D] (N=6144). MODE 1: fp32 row-major out.
template<int MODE>
__global__ __launch_bounds__(256, 2)
void k_gemm_bt(const unsigned short* __restrict__ A,
               const unsigned short* __restrict__ Bt,
               const float* __restrict__ bias,
               float* __restrict__ OutF,
               unsigned short* __restrict__ Qd,
               unsigned short* __restrict__ Kd,
               unsigned short* __restrict__ Vd,
               int M, int N, int K)
{
  __shared__ __align__(16) unsigned short Al[128 * 64];
  __shared__ __align__(16) unsigned short Bl[128 * 64];
  const int t = threadIdx.x;
  const int l = t & 63;
  const int wv = t >> 6;
  const int wm = wv >> 1, wn = wv & 1;
  const int bm = blockIdx.y * 128, bn = blockIdx.x * 128;
  const int lr = l & 15, lg = l >> 4;

  f32x4 acc[4][4];
  #pragma unroll
  for (int i = 0; i < 4; ++i)
    #pragma unroll
    for (int j = 0; j < 4; ++j)
      acc[i][j] = f32x4{0.f, 0.f, 0.f, 0.f};

  for (int k0 = 0; k0 < K; k0 += 64) {
    // stage 128x64 A-tile and B-tile; LDS linear dest, swizzled global source:
    // LDS 16B-chunk (row, c) holds logical k-chunk (c ^ (row&7))
    #pragma unroll
    for (int i = 0; i < 4; ++i) {
      const int Cc = i * 256 + t;          // 16B chunk id 0..1023
      const int row = Cc >> 3;
      const int kc = (Cc & 7) ^ (row & 7);
      async16(&Al[(i * 256 + (t & 192)) * 8], &A[(size_t)(bm + row) * K + k0 + kc * 8]);
      async16(&Bl[(i * 256 + (t & 192)) * 8], &Bt[(size_t)(bn + row) * K + k0 + kc * 8]);
    }
    __syncthreads();
    #pragma unroll
    for (int kk = 0; kk < 2; ++kk) {
      s16x8 af[4], bfr[4];
      #pragma unroll
      for (int mb = 0; mb < 4; ++mb) {
        const int row = wm * 64 + mb * 16 + lr;
        const int ch = (kk * 4 + lg) ^ (row & 7);
        af[mb] = *(const s16x8*)&Al[row * 64 + ch * 8];
      }
      #pragma unroll
      for (int nb = 0; nb < 4; ++nb) {
        const int row = wn * 64 + nb * 16 + lr;
        const int ch = (kk * 4 + lg) ^ (row & 7);
        bfr[nb] = *(const s16x8*)&Bl[row * 64 + ch * 8];
      }
      __builtin_amdgcn_s_setprio(1);
      #pragma unroll
      for (int mb = 0; mb < 4; ++mb)
        #pragma unroll
        for (int nb = 0; nb < 4; ++nb)
          acc[mb][nb] = __builtin_amdgcn_mfma_f32_16x16x32_bf16(af[mb], bfr[nb], acc[mb][nb], 0, 0, 0);
      __builtin_amdgcn_s_setprio(0);
    }
    __syncthreads();
  }

  // epilogue; C/D layout: col = lane&15, row = (lane>>4)*4 + reg  [m89-verified]
  #pragma unroll
  for (int mb = 0; mb < 4; ++mb) {
    #pragma unroll
    for (int nb = 0; nb < 4; ++nb) {
      const int col = bn + wn * 64 + nb * 16 + lr;
      const float bv = bias[col];
      #pragma unroll
      for (int r = 0; r < 4; ++r) {
        const int row = bm + wm * 64 + mb * 16 + lg * 4 + r;
        const float v = acc[mb][nb][r] + bv;
        if (MODE == 1) {
          OutF[(size_t)row * N + col] = v;
        } else {
          const int which = col >> 11;         // 0=q 1=k 2=v (uniform per block)
          const int cc = col & 2047;
          const int h = cc >> 7, d = cc & 127;
          const int b = row >> 11, tp = row & 2047;
          unsigned short* dst = (which == 0) ? Qd : (which == 1 ? Kd : Vd);
          dst[(((size_t)(b * NH + h)) * NT + tp) * HD + d] = f2bf(v);
        }
      }
    }
  }
}

// ---------------- flash attention: 4 waves x 16 q-rows, KV tile 64 ----------------
// Causal-balanced: grid.x = 16 pairs; block i processes q-tiles {i, 31-i}
// sequentially -> constant 33 kv-iters per block (was 1..32, a 32:1 imbalance).
// swapped S^T = mfma(K, Q): lane owns q = lane&15; keys live at (lane>>4)*4+reg.
// PV: y^T = mfma(V^T via ds_read_b64_tr_b16 from subtiled V_lds, P^T from regs).
// tr_read semantics: each lane reads contiguous 8B at its own addr; the 16-lane
// group's 128B window is a row-major [4][16] bf16 matrix, lane l gets column l&15.
__global__ __launch_bounds__(256, 4)
void k_attn(const unsigned short* __restrict__ Q,
            const unsigned short* __restrict__ Kg,
            const unsigned short* __restrict__ Vg,
            unsigned short* __restrict__ Yatt)   // att [BT][NC] bf16
{
  __shared__ __align__(16) unsigned short Kl[64 * 128];  // [key][d], 16B-chunk-swizzled
  __shared__ __align__(16) unsigned short Vl[64 * 128];  // subtiled [key/4][d/16][4][16]
  const int pair = blockIdx.x;        // 0..15
  const int bh = blockIdx.y;          // 0..63
  const int b = bh >> 4, h = bh & 15;
  const int t = threadIdx.x, l = t & 63, wv = t >> 6;
  const int lr = l & 15, lg = l >> 4;
  const size_t hoff = (size_t)bh * NT * HD;
  const unsigned short* Qh = Q + hoff;
  const unsigned short* Kh = Kg + hoff;
  const unsigned short* Vh = Vg + hoff;
  const uint32_t vbase = lds_off(Vl);

  #pragma unroll 1
  for (int rep = 0; rep < 2; ++rep) {
    const int qb = rep ? (31 - pair) : pair;
    const int q0w = qb * 64 + wv * 16;
    const int qrow = q0w + lr;

    s16x8 qf[4];  // Q[qrow][m*32 + lg*8 .. +8]
    #pragma unroll
    for (int m = 0; m < 4; ++m)
      qf[m] = *(const s16x8*)(Qh + (size_t)qrow * HD + m * 32 + lg * 8);

    f32x4 yt[8];  // y^T: 8 d-tiles of 16; lane: q=lr, d = n*16 + lg*4 + r
    #pragma unroll
    for (int n = 0; n < 8; ++n) yt[n] = f32x4{0.f, 0.f, 0.f, 0.f};
    float mrun = -1e30f, lrun = 0.f;

    const int nkv = qb + 1;
    for (int kv = 0; kv < nkv; ++kv) {
      const int kv0 = kv * 64;
      #pragma unroll
      for (int i = 0; i < 4; ++i) {
        const int Cc = i * 256 + t;
        {  // K tile: row-major [64][128], 16B chunks swizzled with (row&7)
          const int krow = Cc >> 4;
          const int kc = (Cc & 15) ^ (krow & 7);
          async16(&Kl[(i * 256 + (t & 192)) * 8], &Kh[(size_t)(kv0 + krow) * HD + kc * 8]);
        }
        {  // V tile: subtile S = kq*8+dq holds [4 keys][16 d] row-major
          const int S = Cc >> 3, c8 = Cc & 7;
          const int kq = S >> 3, dq = S & 7;
          const int vk = kq * 4 + (c8 >> 1), vd = dq * 16 + (c8 & 1) * 8;
          async16(&Vl[(i * 256 + (t & 192)) * 8], &Vh[(size_t)(kv0 + vk) * HD + vd]);
        }
      }
      __syncthreads();

      // S^T tiles: 4 key-tiles of 16, k-dim = d (4 chunks of 32)
      f32x4 st[4];
      __builtin_amdgcn_s_setprio(1);
      #pragma unroll
      for (int kt = 0; kt < 4; ++kt) {
        f32x4 a = f32x4{0.f, 0.f, 0.f, 0.f};
        const int krow = kt * 16 + lr;
        #pragma unroll
        for (int m = 0; m < 4; ++m) {
          const int ch = (m * 4 + lg) ^ (krow & 7);
          s16x8 kf = *(const s16x8*)&Kl[krow * 128 + ch * 8];
          a = __builtin_amdgcn_mfma_f32_16x16x32_bf16(kf, qf[m], a, 0, 0, 0);
        }
        st[kt] = a;
      }
      __builtin_amdgcn_s_setprio(0);

      // causal mask (only needed near diagonal)
      if (kv0 + 63 > q0w) {
        #pragma unroll
        for (int kt = 0; kt < 4; ++kt)
          #pragma unroll
          for (int r = 0; r < 4; ++r) {
            const int key = kv0 + kt * 16 + lg * 4 + r;
            if (key > qrow) st[kt][r] = -3.0e38f;
          }
      }

      // online softmax (S already scaled by 1/sqrt(D)*log2e via Q)
      float tm = -3.0e38f;
      #pragma unroll
      for (int kt = 0; kt < 4; ++kt)
        #pragma unroll
        for (int r = 0; r < 4; ++r) tm = fmaxf(tm, st[kt][r]);
      tm = fmaxf(tm, __shfl_xor(tm, 16));
      tm = fmaxf(tm, __shfl_xor(tm, 32));
      const float mnew = fmaxf(mrun, tm);
      const float fsc = exp2f(mrun - mnew);
      mrun = mnew;
      lrun *= fsc;
      #pragma unroll
      for (int n = 0; n < 8; ++n)
        #pragma unroll
        for (int r = 0; r < 4; ++r) yt[n][r] *= fsc;

      unsigned short pb[16];
      float psum = 0.f;
      #pragma unroll
      for (int kt = 0; kt < 4; ++kt)
        #pragma unroll
        for (int r = 0; r < 4; ++r) {
          const float p = exp2f(st[kt][r] - mnew);
          psum += p;
          pb[kt * 4 + r] = f2bf(p);
        }
      lrun += psum;

      // pack P^T frags: element j of k-group gk = key gk*32 + 16*(j>>2) + lg*4 + (j&3)
      s16x8 pf[2];
      #pragma unroll
      for (int gk = 0; gk < 2; ++gk)
        #pragma unroll
        for (int j = 0; j < 8; ++j)
          pf[gk][j] = (short)pb[(gk * 2 + (j >> 2)) * 4 + (j & 3)];

      // PV: yt[n] += V^T_frag * pf[gk]; V^T frag elem j = V[key gk*32+16*(j>>2)+lg*4+(j&3)][n*16+lr]
      #pragma unroll
      for (int gk = 0; gk < 2; ++gk) {
        s16x4 va[8], vb2[8];
        #pragma unroll
        for (int n = 0; n < 8; ++n) {
          // subtile S = (kq = gk*8+lg)*8 + (dq = n); lane addr = S*128 + lr*8 bytes
          const uint32_t a0 = vbase + ((uint32_t)((gk * 8 + lg) * 8 + n)) * 128 + (uint32_t)lr * 8;
          asm volatile("ds_read_b64_tr_b16 %0, %1" : "=v"(va[n])  : "v"(a0));
          asm volatile("ds_read_b64_tr_b16 %0, %1" : "=v"(vb2[n]) : "v"(a0 + 4096));
        }
        asm volatile("s_waitcnt lgkmcnt(0)" ::: "memory");
        __builtin_amdgcn_sched_barrier(0);
        __builtin_amdgcn_s_setprio(1);
        #pragma unroll
        for (int n = 0; n < 8; ++n) {
          s16x8 vf;
          vf[0] = va[n][0];  vf[1] = va[n][1];  vf[2] = va[n][2];  vf[3] = va[n][3];
          vf[4] = vb2[n][0]; vf[5] = vb2[n][1]; vf[6] = vb2[n][2]; vf[7] = vb2[n][3];
          yt[n] = __builtin_amdgcn_mfma_f32_16x16x32_bf16(vf, pf[gk], yt[n], 0, 0, 0);
        }
        __builtin_amdgcn_s_setprio(0);
      }
      __syncthreads();
    }

    // finalize: reduce l across the 4 lane-groups, scale, write att row
    lrun += __shfl_xor(lrun, 16);
    lrun += __shfl_xor(lrun, 32);
    const float inv = 1.f / lrun;
    unsigned short* yrow = Yatt + (size_t)(b * NT + q0w + lr) * NC + h * HD;
    #pragma unroll
    for (int n = 0; n < 8; ++n)
      #pragma unroll
      for (int r = 0; r < 4; ++r)
        yrow[n * 16 + lg * 4 + r] = f2bf(yt[n][r] * inv);
  }
}

extern "C" void kernel_launch(void* const* d_in, const int* in_sizes, int n_in,
                              void* d_out, int out_size, void* d_ws, size_t ws_size,
                              hipStream_t stream) {
  (void)in_sizes; (void)n_in; (void)out_size; (void)ws_size;
  const float* x     = (const float*)d_in[0];
  const float* Wqkv  = (const float*)d_in[1];
  const float* bqkv  = (const float*)d_in[2];
  const float* Wproj = (const float*)d_in[3];
  const float* bproj = (const float*)d_in[4];
  float* out = (float*)d_out;
  char* ws = (char*)d_ws;

  // workspace layout (160 MB total)
  unsigned short* xb     = (unsigned short*)(ws);               // 32MB  [BT][NC] bf16
  unsigned short* WqkvT  = (unsigned short*)(ws + 33554432);    // 24MB  [6144][2048]
  unsigned short* WprojT = (unsigned short*)(ws + 58720256);    // 8MB   [2048][2048]
  unsigned short* Qb     = (unsigned short*)(ws + 67108864);    // 32MB  [BH][T][D]
  unsigned short* Kb     = (unsigned short*)(ws + 100663296);   // 32MB
  unsigned short* Vb     = (unsigned short*)(ws + 134217728);   // 32MB
  unsigned short* att    = xb;  // reuse (xb dead after GEMM1)

  k_convert_bf16<<<dim3(8192), dim3(256), 0, stream>>>(x, xb, BT * NC / 8);
  k_transpose_bf16<<<dim3(96, 32), dim3(256), 0, stream>>>(Wqkv, WqkvT, NC, 3 * NC);
  k_transpose_bf16<<<dim3(32, 32), dim3(256), 0, stream>>>(Wproj, WprojT, NC, NC);
  k_gemm_bt<0><<<dim3(48, 64), dim3(256), 0, stream>>>(xb, WqkvT, bqkv, nullptr, Qb, Kb, Vb, BT, 3 * NC, NC);
  k_rope<<<dim3(32768), dim3(256), 0, stream>>>(Qb, Kb);
  k_attn<<<dim3(16, 64), dim3(256), 0, stream>>>(Qb, Kb, Vb, att);
  k_gemm_bt<1><<<dim3(16, 64), dim3(256), 0, stream>>>(att, WprojT, bproj, out, nullptr, nullptr, nullptr, BT, NC, NC);
}

// Round 4
// 476.154 us; speedup vs baseline: 1.5685x; 1.5685x over previous
//
#include <hip/hip_runtime.h>
#include <hip/hip_bf16.h>
#include <stdint.h>
#include <math.h>

// Problem constants
#define NB 4
#define NT 2048
#define NC 2048
#define NH 16
#define HD 128
#define BT (NB*NT)   // 8192

typedef __attribute__((ext_vector_type(8))) short s16x8;
typedef __attribute__((ext_vector_type(4))) short s16x4;
typedef __attribute__((ext_vector_type(4))) float f32x4;

typedef __attribute__((address_space(1))) void as1_void;
typedef __attribute__((address_space(3))) void as3_void;

static __device__ __forceinline__ unsigned short f2bf(float f) {
  union { float f; uint32_t u; } v; v.f = f;
  return (unsigned short)((v.u + 0x7fffu + ((v.u >> 16) & 1u)) >> 16);
}
static __device__ __forceinline__ float bf2f(unsigned short u) {
  union { uint32_t u; float f; } v; v.u = ((uint32_t)u) << 16;
  return v.f;
}
static __device__ __forceinline__ void async16(unsigned short* lds, const unsigned short* g) {
  __builtin_amdgcn_global_load_lds((as1_void*)g, (as3_void*)lds, 16, 0, 0);
}
static __device__ __forceinline__ uint32_t lds_off(void* p) {
  return (uint32_t)(size_t)(as3_void*)p;
}

// ---------------- fp32 -> bf16 convert (vectorized, 8 elems/thread) ----------------
__global__ void k_convert_bf16(const float* __restrict__ in, unsigned short* __restrict__ out, int n8) {
  int i = blockIdx.x * blockDim.x + threadIdx.x;
  if (i >= n8) return;
  const float4* p = (const float4*)in + (size_t)i * 2;
  float4 a = p[0], b = p[1];
  union { unsigned short s[8]; uint4 u; } o;
  o.s[0] = f2bf(a.x); o.s[1] = f2bf(a.y); o.s[2] = f2bf(a.z); o.s[3] = f2bf(a.w);
  o.s[4] = f2bf(b.x); o.s[5] = f2bf(b.y); o.s[6] = f2bf(b.z); o.s[7] = f2bf(b.w);
  ((uint4*)out)[i] = o.u;
}

// ---------------- transpose + convert: W [K][N] fp32 -> WT [N][K] bf16 ----------------
__global__ void k_transpose_bf16(const float* __restrict__ W, unsigned short* __restrict__ WT, int K, int N) {
  __shared__ unsigned short tile[64][65];
  const int k0 = blockIdx.y * 64, n0 = blockIdx.x * 64;
  const int t = threadIdx.x;
  const int jj = t & 63, base_i = t >> 6;
  #pragma unroll
  for (int p = 0; p < 16; ++p) {
    int i = p * 4 + base_i;
    tile[i][jj] = f2bf(W[(size_t)(k0 + i) * N + n0 + jj]);
  }
  __syncthreads();
  #pragma unroll
  for (int p = 0; p < 16; ++p) {
    int j = p * 4 + base_i;
    WT[(size_t)(n0 + j) * K + k0 + jj] = tile[jj][j];
  }
}

// ---------------- RoPE in-place on Q,K [BH][T][D]; fold scale*log2e into Q ----------------
__global__ void k_rope(unsigned short* __restrict__ Q, unsigned short* __restrict__ Kb) {
  int idx = blockIdx.x * 256 + threadIdx.x;  // over BH*T*64
  int d = idx & 63;
  int tpos = (idx >> 6) & (NT - 1);
  int bh = idx >> 17;
  size_t o = ((size_t)bh * NT + tpos) * HD + d;
  float invf = exp2f(-(float)d * 0.2076205059304602f);  // log2(10000)/64
  float ang = (float)tpos * invf;
  float s, c;
  sincosf(ang, &s, &c);
  float q1 = bf2f(Q[o]),  q2 = bf2f(Q[o + 64]);
  float k1 = bf2f(Kb[o]), k2 = bf2f(Kb[o + 64]);
  const float qs = 0.08838834764831845f * 1.4426950408889634f;  // (1/sqrt(128))*log2e
  Q[o]       = f2bf((q1 * c - q2 * s) * qs);
  Q[o + 64]  = f2bf((q2 * c + q1 * s) * qs);
  Kb[o]      = f2bf(k1 * c - k2 * s);
  Kb[o + 64] = f2bf(k2 * c + k1 * s);
}

// ---------------- GEMM: C[M][N] = A[M][K] * Bt[N][K]^T + bias ----------------
// MODE 0: scatter bf16 into Q/K/V [B][H][T][D] (N=6144). MODE 1: fp32 row-major out.
template<int MODE>
__global__ __launch_bounds__(256, 2)
void k_gemm_bt(const unsigned short* __restrict__ A,
               const unsigned short* __restrict__ Bt,
               const float* __restrict__ bias,
               float* __restrict__ OutF,
               unsigned short* __restrict__ Qd,
               unsigned short* __restrict__ Kd,
               unsigned short* __restrict__ Vd,
               int M, int N, int K)
{
  __shared__ __align__(16) unsigned short Al[128 * 64];
  __shared__ __align__(16) unsigned short Bl[128 * 64];
  const int t = threadIdx.x;
  const int l = t & 63;
  const int wv = t >> 6;
  const int wm = wv >> 1, wn = wv & 1;
  const int bm = blockIdx.y * 128, bn = blockIdx.x * 128;
  const int lr = l & 15, lg = l >> 4;

  f32x4 acc[4][4];
  #pragma unroll
  for (int i = 0; i < 4; ++i)
    #pragma unroll
    for (int j = 0; j < 4; ++j)
      acc[i][j] = f32x4{0.f, 0.f, 0.f, 0.f};

  for (int k0 = 0; k0 < K; k0 += 64) {
    // stage 128x64 A-tile and B-tile; LDS linear dest, swizzled global source:
    // LDS 16B-chunk (row, c) holds logical k-chunk (c ^ (row&7))
    #pragma unroll
    for (int i = 0; i < 4; ++i) {
      const int Cc = i * 256 + t;          // 16B chunk id 0..1023
      const int row = Cc >> 3;
      const int kc = (Cc & 7) ^ (row & 7);
      async16(&Al[(i * 256 + (t & 192)) * 8], &A[(size_t)(bm + row) * K + k0 + kc * 8]);
      async16(&Bl[(i * 256 + (t & 192)) * 8], &Bt[(size_t)(bn + row) * K + k0 + kc * 8]);
    }
    __syncthreads();
    #pragma unroll
    for (int kk = 0; kk < 2; ++kk) {
      s16x8 af[4], bfr[4];
      #pragma unroll
      for (int mb = 0; mb < 4; ++mb) {
        const int row = wm * 64 + mb * 16 + lr;
        const int ch = (kk * 4 + lg) ^ (row & 7);
        af[mb] = *(const s16x8*)&Al[row * 64 + ch * 8];
      }
      #pragma unroll
      for (int nb = 0; nb < 4; ++nb) {
        const int row = wn * 64 + nb * 16 + lr;
        const int ch = (kk * 4 + lg) ^ (row & 7);
        bfr[nb] = *(const s16x8*)&Bl[row * 64 + ch * 8];
      }
      __builtin_amdgcn_s_setprio(1);
      #pragma unroll
      for (int mb = 0; mb < 4; ++mb)
        #pragma unroll
        for (int nb = 0; nb < 4; ++nb)
          acc[mb][nb] = __builtin_amdgcn_mfma_f32_16x16x32_bf16(af[mb], bfr[nb], acc[mb][nb], 0, 0, 0);
      __builtin_amdgcn_s_setprio(0);
    }
    __syncthreads();
  }

  // epilogue; C/D layout: col = lane&15, row = (lane>>4)*4 + reg  [m89-verified]
  #pragma unroll
  for (int mb = 0; mb < 4; ++mb) {
    #pragma unroll
    for (int nb = 0; nb < 4; ++nb) {
      const int col = bn + wn * 64 + nb * 16 + lr;
      const float bv = bias[col];
      #pragma unroll
      for (int r = 0; r < 4; ++r) {
        const int row = bm + wm * 64 + mb * 16 + lg * 4 + r;
        const float v = acc[mb][nb][r] + bv;
        if (MODE == 1) {
          OutF[(size_t)row * N + col] = v;
        } else {
          const int which = col >> 11;         // 0=q 1=k 2=v (uniform per block)
          const int cc = col & 2047;
          const int h = cc >> 7, d = cc & 127;
          const int b = row >> 11, tp = row & 2047;
          unsigned short* dst = (which == 0) ? Qd : (which == 1 ? Kd : Vd);
          dst[(((size_t)(b * NH + h)) * NT + tp) * HD + d] = f2bf(v);
        }
      }
    }
  }
}

// ---------------- flash attention: 4 waves x 16 q-rows, KV tile 64 ----------------
// Causal-balanced: grid = (bh 64, pair 16); block processes q-tiles {pair, 31-pair}
// sequentially -> constant 33 kv-iters per block. Grid layout puts all 16 blocks
// of head bh at linear IDs == bh (mod 64) -> same XCD (round-robin mod 8), so a
// head's K/V stream stays in one L2.
// swapped S^T = mfma(K, Q): lane owns q = lane&15; keys live at (lane>>4)*4+reg.
// PV: y^T = mfma(V^T via ds_read_b64_tr_b16 from subtiled V_lds, P^T from regs).
// tr_read semantics: each lane reads contiguous 8B at its own addr; the 16-lane
// group's 128B window is a row-major [4][16] bf16 matrix, lane l gets column l&15.
__global__ __launch_bounds__(256, 2)
void k_attn(const unsigned short* __restrict__ Q,
            const unsigned short* __restrict__ Kg,
            const unsigned short* __restrict__ Vg,
            unsigned short* __restrict__ Yatt)   // att [BT][NC] bf16
{
  __shared__ __align__(16) unsigned short Kl[64 * 128];  // [key][d], 16B-chunk-swizzled
  __shared__ __align__(16) unsigned short Vl[64 * 128];  // subtiled [key/4][d/16][4][16]
  const int bh = blockIdx.x;          // 0..63  (x-major => same-head blocks same XCD)
  const int pair = blockIdx.y;        // 0..15
  const int b = bh >> 4, h = bh & 15;
  const int t = threadIdx.x, l = t & 63, wv = t >> 6;
  const int lr = l & 15, lg = l >> 4;
  const size_t hoff = (size_t)bh * NT * HD;
  const unsigned short* Qh = Q + hoff;
  const unsigned short* Kh = Kg + hoff;
  const unsigned short* Vh = Vg + hoff;
  const uint32_t vbase = lds_off(Vl);

  #pragma unroll 1
  for (int rep = 0; rep < 2; ++rep) {
    const int qb = rep ? (31 - pair) : pair;
    const int q0w = qb * 64 + wv * 16;
    const int qrow = q0w + lr;

    s16x8 qf[4];  // Q[qrow][m*32 + lg*8 .. +8]
    #pragma unroll
    for (int m = 0; m < 4; ++m)
      qf[m] = *(const s16x8*)(Qh + (size_t)qrow * HD + m * 32 + lg * 8);

    f32x4 yt[8];  // y^T: 8 d-tiles of 16; lane: q=lr, d = n*16 + lg*4 + r
    #pragma unroll
    for (int n = 0; n < 8; ++n) yt[n] = f32x4{0.f, 0.f, 0.f, 0.f};
    float mrun = -1e30f, lrun = 0.f;

    const int nkv = qb + 1;
    for (int kv = 0; kv < nkv; ++kv) {
      const int kv0 = kv * 64;
      #pragma unroll
      for (int i = 0; i < 4; ++i) {
        const int Cc = i * 256 + t;
        {  // K tile: row-major [64][128], 16B chunks swizzled with (row&7)
          const int krow = Cc >> 4;
          const int kc = (Cc & 15) ^ (krow & 7);
          async16(&Kl[(i * 256 + (t & 192)) * 8], &Kh[(size_t)(kv0 + krow) * HD + kc * 8]);
        }
        {  // V tile: subtile S = kq*8+dq holds [4 keys][16 d] row-major
          const int S = Cc >> 3, c8 = Cc & 7;
          const int kq = S >> 3, dq = S & 7;
          const int vk = kq * 4 + (c8 >> 1), vd = dq * 16 + (c8 & 1) * 8;
          async16(&Vl[(i * 256 + (t & 192)) * 8], &Vh[(size_t)(kv0 + vk) * HD + vd]);
        }
      }
      __syncthreads();

      // S^T tiles: 4 key-tiles of 16, k-dim = d (4 chunks of 32)
      f32x4 st[4];
      __builtin_amdgcn_s_setprio(1);
      #pragma unroll
      for (int kt = 0; kt < 4; ++kt) {
        f32x4 a = f32x4{0.f, 0.f, 0.f, 0.f};
        const int krow = kt * 16 + lr;
        #pragma unroll
        for (int m = 0; m < 4; ++m) {
          const int ch = (m * 4 + lg) ^ (krow & 7);
          s16x8 kf = *(const s16x8*)&Kl[krow * 128 + ch * 8];
          a = __builtin_amdgcn_mfma_f32_16x16x32_bf16(kf, qf[m], a, 0, 0, 0);
        }
        st[kt] = a;
      }
      __builtin_amdgcn_s_setprio(0);

      // causal mask (only needed near diagonal)
      if (kv0 + 63 > q0w) {
        #pragma unroll
        for (int kt = 0; kt < 4; ++kt)
          #pragma unroll
          for (int r = 0; r < 4; ++r) {
            const int key = kv0 + kt * 16 + lg * 4 + r;
            if (key > qrow) st[kt][r] = -3.0e38f;
          }
      }

      // online softmax (S already scaled by 1/sqrt(D)*log2e via Q)
      float tm = -3.0e38f;
      #pragma unroll
      for (int kt = 0; kt < 4; ++kt)
        #pragma unroll
        for (int r = 0; r < 4; ++r) tm = fmaxf(tm, st[kt][r]);
      tm = fmaxf(tm, __shfl_xor(tm, 16));
      tm = fmaxf(tm, __shfl_xor(tm, 32));
      const float mnew = fmaxf(mrun, tm);
      const float fsc = exp2f(mrun - mnew);
      mrun = mnew;
      lrun *= fsc;
      #pragma unroll
      for (int n = 0; n < 8; ++n)
        #pragma unroll
        for (int r = 0; r < 4; ++r) yt[n][r] *= fsc;

      unsigned short pb[16];
      float psum = 0.f;
      #pragma unroll
      for (int kt = 0; kt < 4; ++kt)
        #pragma unroll
        for (int r = 0; r < 4; ++r) {
          const float p = exp2f(st[kt][r] - mnew);
          psum += p;
          pb[kt * 4 + r] = f2bf(p);
        }
      lrun += psum;

      // pack P^T frags: element j of k-group gk = key gk*32 + 16*(j>>2) + lg*4 + (j&3)
      s16x8 pf[2];
      #pragma unroll
      for (int gk = 0; gk < 2; ++gk)
        #pragma unroll
        for (int j = 0; j < 8; ++j)
          pf[gk][j] = (short)pb[(gk * 2 + (j >> 2)) * 4 + (j & 3)];

      // PV: yt[n] += V^T_frag * pf[gk]; V^T frag elem j = V[key gk*32+16*(j>>2)+lg*4+(j&3)][n*16+lr]
      #pragma unroll
      for (int gk = 0; gk < 2; ++gk) {
        s16x4 va[8], vb2[8];
        #pragma unroll
        for (int n = 0; n < 8; ++n) {
          // subtile S = (kq = gk*8+lg)*8 + (dq = n); lane addr = S*128 + lr*8 bytes
          const uint32_t a0 = vbase + ((uint32_t)((gk * 8 + lg) * 8 + n)) * 128 + (uint32_t)lr * 8;
          asm volatile("ds_read_b64_tr_b16 %0, %1" : "=v"(va[n])  : "v"(a0));
          asm volatile("ds_read_b64_tr_b16 %0, %1" : "=v"(vb2[n]) : "v"(a0 + 4096));
        }
        asm volatile("s_waitcnt lgkmcnt(0)" ::: "memory");
        __builtin_amdgcn_sched_barrier(0);
        __builtin_amdgcn_s_setprio(1);
        #pragma unroll
        for (int n = 0; n < 8; ++n) {
          s16x8 vf;
          vf[0] = va[n][0];  vf[1] = va[n][1];  vf[2] = va[n][2];  vf[3] = va[n][3];
          vf[4] = vb2[n][0]; vf[5] = vb2[n][1]; vf[6] = vb2[n][2]; vf[7] = vb2[n][3];
          yt[n] = __builtin_amdgcn_mfma_f32_16x16x32_bf16(vf, pf[gk], yt[n], 0, 0, 0);
        }
        __builtin_amdgcn_s_setprio(0);
      }
      __syncthreads();
    }

    // finalize: reduce l across the 4 lane-groups, scale, write att row
    lrun += __shfl_xor(lrun, 16);
    lrun += __shfl_xor(lrun, 32);
    const float inv = 1.f / lrun;
    unsigned short* yrow = Yatt + (size_t)(b * NT + q0w + lr) * NC + h * HD;
    #pragma unroll
    for (int n = 0; n < 8; ++n)
      #pragma unroll
      for (int r = 0; r < 4; ++r)
        yrow[n * 16 + lg * 4 + r] = f2bf(yt[n][r] * inv);
  }
}

extern "C" void kernel_launch(void* const* d_in, const int* in_sizes, int n_in,
                              void* d_out, int out_size, void* d_ws, size_t ws_size,
                              hipStream_t stream) {
  (void)in_sizes; (void)n_in; (void)out_size; (void)ws_size;
  const float* x     = (const float*)d_in[0];
  const float* Wqkv  = (const float*)d_in[1];
  const float* bqkv  = (const float*)d_in[2];
  const float* Wproj = (const float*)d_in[3];
  const float* bproj = (const float*)d_in[4];
  float* out = (float*)d_out;
  char* ws = (char*)d_ws;

  // workspace layout (160 MB total)
  unsigned short* xb     = (unsigned short*)(ws);               // 32MB  [BT][NC] bf16
  unsigned short* WqkvT  = (unsigned short*)(ws + 33554432);    // 24MB  [6144][2048]
  unsigned short* WprojT = (unsigned short*)(ws + 58720256);    // 8MB   [2048][2048]
  unsigned short* Qb     = (unsigned short*)(ws + 67108864);    // 32MB  [BH][T][D]
  unsigned short* Kb     = (unsigned short*)(ws + 100663296);   // 32MB
  unsigned short* Vb     = (unsigned short*)(ws + 134217728);   // 32MB
  unsigned short* att    = xb;  // reuse (xb dead after GEMM1)

  k_convert_bf16<<<dim3(8192), dim3(256), 0, stream>>>(x, xb, BT * NC / 8);
  k_transpose_bf16<<<dim3(96, 32), dim3(256), 0, stream>>>(Wqkv, WqkvT, NC, 3 * NC);
  k_transpose_bf16<<<dim3(32, 32), dim3(256), 0, stream>>>(Wproj, WprojT, NC, NC);
  k_gemm_bt<0><<<dim3(48, 64), dim3(256), 0, stream>>>(xb, WqkvT, bqkv, nullptr, Qb, Kb, Vb, BT, 3 * NC, NC);
  k_rope<<<dim3(32768), dim3(256), 0, stream>>>(Qb, Kb);
  k_attn<<<dim3(64, 16), dim3(256), 0, stream>>>(Qb, Kb, Vb, att);
  k_gemm_bt<1><<<dim3(16, 64), dim3(256), 0, stream>>>(att, WprojT, bproj, out, nullptr, nullptr, nullptr, BT, NC, NC);
}

// Round 5
// 470.841 us; speedup vs baseline: 1.5862x; 1.0113x over previous
//
#include <hip/hip_runtime.h>
#include <hip/hip_bf16.h>
#include <stdint.h>
#include <math.h>

// Problem constants
#define NB 4
#define NT 2048
#define NC 2048
#define NH 16
#define HD 128
#define BT (NB*NT)   // 8192

typedef __attribute__((ext_vector_type(8))) short s16x8;
typedef __attribute__((ext_vector_type(4))) short s16x4;
typedef __attribute__((ext_vector_type(4))) float f32x4;

typedef __attribute__((address_space(1))) void as1_void;
typedef __attribute__((address_space(3))) void as3_void;

static __device__ __forceinline__ unsigned short f2bf(float f) {
  union { float f; uint32_t u; } v; v.f = f;
  return (unsigned short)((v.u + 0x7fffu + ((v.u >> 16) & 1u)) >> 16);
}
static __device__ __forceinline__ float bf2f(unsigned short u) {
  union { uint32_t u; float f; } v; v.u = ((uint32_t)u) << 16;
  return v.f;
}
static __device__ __forceinline__ void async16(unsigned short* lds, const unsigned short* g) {
  __builtin_amdgcn_global_load_lds((as1_void*)g, (as3_void*)lds, 16, 0, 0);
}
static __device__ __forceinline__ uint32_t lds_off(void* p) {
  return (uint32_t)(size_t)(as3_void*)p;
}

// ---------------- fp32 -> bf16 convert (vectorized, 8 elems/thread) ----------------
__global__ void k_convert_bf16(const float* __restrict__ in, unsigned short* __restrict__ out, int n8) {
  int i = blockIdx.x * blockDim.x + threadIdx.x;
  if (i >= n8) return;
  const float4* p = (const float4*)in + (size_t)i * 2;
  float4 a = p[0], b = p[1];
  union { unsigned short s[8]; uint4 u; } o;
  o.s[0] = f2bf(a.x); o.s[1] = f2bf(a.y); o.s[2] = f2bf(a.z); o.s[3] = f2bf(a.w);
  o.s[4] = f2bf(b.x); o.s[5] = f2bf(b.y); o.s[6] = f2bf(b.z); o.s[7] = f2bf(b.w);
  ((uint4*)out)[i] = o.u;
}

// ---------------- transpose + convert: W [K][N] fp32 -> WT [N][K] bf16 ----------------
__global__ void k_transpose_bf16(const float* __restrict__ W, unsigned short* __restrict__ WT, int K, int N) {
  __shared__ unsigned short tile[64][65];
  const int k0 = blockIdx.y * 64, n0 = blockIdx.x * 64;
  const int t = threadIdx.x;
  const int jj = t & 63, base_i = t >> 6;
  #pragma unroll
  for (int p = 0; p < 16; ++p) {
    int i = p * 4 + base_i;
    tile[i][jj] = f2bf(W[(size_t)(k0 + i) * N + n0 + jj]);
  }
  __syncthreads();
  #pragma unroll
  for (int p = 0; p < 16; ++p) {
    int j = p * 4 + base_i;
    WT[(size_t)(n0 + j) * K + k0 + jj] = tile[jj][j];
  }
}

// ---------------- RoPE in-place on Q,K [BH][T][D]; fold scale*log2e into Q ----------------
__global__ void k_rope(unsigned short* __restrict__ Q, unsigned short* __restrict__ Kb) {
  int idx = blockIdx.x * 256 + threadIdx.x;  // over BH*T*64
  int d = idx & 63;
  int tpos = (idx >> 6) & (NT - 1);
  int bh = idx >> 17;
  size_t o = ((size_t)bh * NT + tpos) * HD + d;
  float invf = exp2f(-(float)d * 0.2076205059304602f);  // log2(10000)/64
  float ang = (float)tpos * invf;
  float s, c;
  sincosf(ang, &s, &c);
  float q1 = bf2f(Q[o]),  q2 = bf2f(Q[o + 64]);
  float k1 = bf2f(Kb[o]), k2 = bf2f(Kb[o + 64]);
  const float qs = 0.08838834764831845f * 1.4426950408889634f;  // (1/sqrt(128))*log2e
  Q[o]       = f2bf((q1 * c - q2 * s) * qs);
  Q[o + 64]  = f2bf((q2 * c + q1 * s) * qs);
  Kb[o]      = f2bf(k1 * c - k2 * s);
  Kb[o + 64] = f2bf(k2 * c + k1 * s);
}

// ---------------- GEMM 256x256, BK=64, 512 thr / 8 waves (2Mx4N), dbuf LDS ----------------
// Counted-vmcnt pipeline (T3+T4): STAGE(t+1) -> vmcnt(8) -> raw barrier -> compute(t)
// -> raw barrier. Raw s_barrier (NOT __syncthreads) so next tile's 8 loads stay in
// flight across the barrier. Chunk-XOR swizzle (kc = c ^ (row&7)) on the global
// source keeps LDS dest linear for global_load_lds; inverse XOR on ds_read.
// MODE 0: scatter bf16 into Q/K/V [B][H][T][D]. MODE 1: fp32 row-major out.
template<int MODE>
__global__ __launch_bounds__(512, 2)
void k_gemm256(const unsigned short* __restrict__ A,
               const unsigned short* __restrict__ Bt,
               const float* __restrict__ bias,
               float* __restrict__ OutF,
               unsigned short* __restrict__ Qd,
               unsigned short* __restrict__ Kd,
               unsigned short* __restrict__ Vd,
               int M, int N, int K)
{
  __shared__ __align__(16) unsigned short Al[2][256 * 64];
  __shared__ __align__(16) unsigned short Bl[2][256 * 64];
  const int t = threadIdx.x;
  const int l = t & 63;
  const int wv = t >> 6;
  const int wm = wv >> 2, wn = wv & 3;     // 2 x 4 wave grid; wave tile 128x64
  const int bm = blockIdx.y * 256, bn = blockIdx.x * 256;
  const int lr = l & 15, lg = l >> 4;

  f32x4 acc[8][4];
  #pragma unroll
  for (int i = 0; i < 8; ++i)
    #pragma unroll
    for (int j = 0; j < 4; ++j)
      acc[i][j] = f32x4{0.f, 0.f, 0.f, 0.f};

  const int ubase = (t & 448) * 8;         // wave-uniform LDS chunk base (elements)

  auto stage = [&](int buf, int k0) {
    #pragma unroll
    for (int i = 0; i < 4; ++i) {
      const int Cc = i * 512 + t;          // 16B chunk id 0..2047
      const int row = Cc >> 3;             // 0..255
      const int kc = (Cc & 7) ^ (row & 7);
      async16(&Al[buf][(i * 512) * 8 + ubase], &A[(size_t)(bm + row) * K + k0 + kc * 8]);
      async16(&Bl[buf][(i * 512) * 8 + ubase], &Bt[(size_t)(bn + row) * K + k0 + kc * 8]);
    }
  };

  auto compute = [&](int buf) {
    #pragma unroll
    for (int kk = 0; kk < 2; ++kk) {
      s16x8 af[8], bfr[4];
      #pragma unroll
      for (int mi = 0; mi < 8; ++mi) {
        const int row = wm * 128 + mi * 16 + lr;
        const int ch = (kk * 4 + lg) ^ (row & 7);
        af[mi] = *(const s16x8*)&Al[buf][row * 64 + ch * 8];
      }
      #pragma unroll
      for (int ni = 0; ni < 4; ++ni) {
        const int row = wn * 64 + ni * 16 + lr;
        const int ch = (kk * 4 + lg) ^ (row & 7);
        bfr[ni] = *(const s16x8*)&Bl[buf][row * 64 + ch * 8];
      }
      __builtin_amdgcn_s_setprio(1);
      #pragma unroll
      for (int mi = 0; mi < 8; ++mi)
        #pragma unroll
        for (int ni = 0; ni < 4; ++ni)
          acc[mi][ni] = __builtin_amdgcn_mfma_f32_16x16x32_bf16(af[mi], bfr[ni], acc[mi][ni], 0, 0, 0);
      __builtin_amdgcn_s_setprio(0);
    }
  };

  stage(0, 0);
  const int nkt = K >> 6;
  int cur = 0;
  #pragma unroll 1
  for (int tt = 0; tt < nkt - 1; ++tt) {
    stage(cur ^ 1, (tt + 1) << 6);
    asm volatile("s_waitcnt vmcnt(8)" ::: "memory");
    __builtin_amdgcn_s_barrier();
    compute(cur);
    __builtin_amdgcn_s_barrier();
    cur ^= 1;
  }
  asm volatile("s_waitcnt vmcnt(0)" ::: "memory");
  __builtin_amdgcn_s_barrier();
  compute(cur);

  // epilogue; C/D layout: col = lane&15, row = (lane>>4)*4 + reg  [m89-verified]
  #pragma unroll
  for (int mi = 0; mi < 8; ++mi) {
    #pragma unroll
    for (int ni = 0; ni < 4; ++ni) {
      const int col = bn + wn * 64 + ni * 16 + lr;
      const float bv = bias[col];
      #pragma unroll
      for (int r = 0; r < 4; ++r) {
        const int row = bm + wm * 128 + mi * 16 + lg * 4 + r;
        const float v = acc[mi][ni][r] + bv;
        if (MODE == 1) {
          OutF[(size_t)row * N + col] = v;
        } else {
          const int which = col >> 11;         // 0=q 1=k 2=v (uniform per block: 2048%256==0)
          const int cc = col & 2047;
          const int h = cc >> 7, d = cc & 127;
          const int b = row >> 11, tp = row & 2047;
          unsigned short* dst = (which == 0) ? Qd : (which == 1 ? Kd : Vd);
          dst[(((size_t)(b * NH + h)) * NT + tp) * HD + d] = f2bf(v);
        }
      }
    }
  }
}

// ---------------- flash attention: 4 waves x 16 q-rows, KV tile 64 ----------------
// Causal-balanced: grid = (bh 64, pair 16); block processes q-tiles {pair, 31-pair}
// sequentially -> constant 33 kv-iters per block. Grid layout puts all 16 blocks
// of head bh at linear IDs == bh (mod 64) -> same XCD (round-robin mod 8), so a
// head's K/V stream stays in one L2.
// swapped S^T = mfma(K, Q): lane owns q = lane&15; keys live at (lane>>4)*4+reg.
// PV: y^T = mfma(V^T via ds_read_b64_tr_b16 from subtiled V_lds, P^T from regs).
// tr_read semantics: each lane reads contiguous 8B at its own addr; the 16-lane
// group's 128B window is a row-major [4][16] bf16 matrix, lane l gets column l&15.
__global__ __launch_bounds__(256, 2)
void k_attn(const unsigned short* __restrict__ Q,
            const unsigned short* __restrict__ Kg,
            const unsigned short* __restrict__ Vg,
            unsigned short* __restrict__ Yatt)   // att [BT][NC] bf16
{
  __shared__ __align__(16) unsigned short Kl[64 * 128];  // [key][d], 16B-chunk-swizzled
  __shared__ __align__(16) unsigned short Vl[64 * 128];  // subtiled [key/4][d/16][4][16]
  const int bh = blockIdx.x;          // 0..63  (x-major => same-head blocks same XCD)
  const int pair = blockIdx.y;        // 0..15
  const int b = bh >> 4, h = bh & 15;
  const int t = threadIdx.x, l = t & 63, wv = t >> 6;
  const int lr = l & 15, lg = l >> 4;
  const size_t hoff = (size_t)bh * NT * HD;
  const unsigned short* Qh = Q + hoff;
  const unsigned short* Kh = Kg + hoff;
  const unsigned short* Vh = Vg + hoff;
  const uint32_t vbase = lds_off(Vl);

  #pragma unroll 1
  for (int rep = 0; rep < 2; ++rep) {
    const int qb = rep ? (31 - pair) : pair;
    const int q0w = qb * 64 + wv * 16;
    const int qrow = q0w + lr;

    s16x8 qf[4];  // Q[qrow][m*32 + lg*8 .. +8]
    #pragma unroll
    for (int m = 0; m < 4; ++m)
      qf[m] = *(const s16x8*)(Qh + (size_t)qrow * HD + m * 32 + lg * 8);

    f32x4 yt[8];  // y^T: 8 d-tiles of 16; lane: q=lr, d = n*16 + lg*4 + r
    #pragma unroll
    for (int n = 0; n < 8; ++n) yt[n] = f32x4{0.f, 0.f, 0.f, 0.f};
    float mrun = -1e30f, lrun = 0.f;

    const int nkv = qb + 1;
    for (int kv = 0; kv < nkv; ++kv) {
      const int kv0 = kv * 64;
      #pragma unroll
      for (int i = 0; i < 4; ++i) {
        const int Cc = i * 256 + t;
        {  // K tile: row-major [64][128], 16B chunks swizzled with (row&7)
          const int krow = Cc >> 4;
          const int kc = (Cc & 15) ^ (krow & 7);
          async16(&Kl[(i * 256 + (t & 192)) * 8], &Kh[(size_t)(kv0 + krow) * HD + kc * 8]);
        }
        {  // V tile: subtile S = kq*8+dq holds [4 keys][16 d] row-major
          const int S = Cc >> 3, c8 = Cc & 7;
          const int kq = S >> 3, dq = S & 7;
          const int vk = kq * 4 + (c8 >> 1), vd = dq * 16 + (c8 & 1) * 8;
          async16(&Vl[(i * 256 + (t & 192)) * 8], &Vh[(size_t)(kv0 + vk) * HD + vd]);
        }
      }
      __syncthreads();

      // S^T tiles: 4 key-tiles of 16, k-dim = d (4 chunks of 32)
      f32x4 st[4];
      __builtin_amdgcn_s_setprio(1);
      #pragma unroll
      for (int kt = 0; kt < 4; ++kt) {
        f32x4 a = f32x4{0.f, 0.f, 0.f, 0.f};
        const int krow = kt * 16 + lr;
        #pragma unroll
        for (int m = 0; m < 4; ++m) {
          const int ch = (m * 4 + lg) ^ (krow & 7);
          s16x8 kf = *(const s16x8*)&Kl[krow * 128 + ch * 8];
          a = __builtin_amdgcn_mfma_f32_16x16x32_bf16(kf, qf[m], a, 0, 0, 0);
        }
        st[kt] = a;
      }
      __builtin_amdgcn_s_setprio(0);

      // causal mask (only needed near diagonal)
      if (kv0 + 63 > q0w) {
        #pragma unroll
        for (int kt = 0; kt < 4; ++kt)
          #pragma unroll
          for (int r = 0; r < 4; ++r) {
            const int key = kv0 + kt * 16 + lg * 4 + r;
            if (key > qrow) st[kt][r] = -3.0e38f;
          }
      }

      // online softmax (S already scaled by 1/sqrt(D)*log2e via Q)
      float tm = -3.0e38f;
      #pragma unroll
      for (int kt = 0; kt < 4; ++kt)
        #pragma unroll
        for (int r = 0; r < 4; ++r) tm = fmaxf(tm, st[kt][r]);
      tm = fmaxf(tm, __shfl_xor(tm, 16));
      tm = fmaxf(tm, __shfl_xor(tm, 32));
      const float mnew = fmaxf(mrun, tm);
      const float fsc = exp2f(mrun - mnew);
      mrun = mnew;
      lrun *= fsc;
      #pragma unroll
      for (int n = 0; n < 8; ++n)
        #pragma unroll
        for (int r = 0; r < 4; ++r) yt[n][r] *= fsc;

      unsigned short pb[16];
      float psum = 0.f;
      #pragma unroll
      for (int kt = 0; kt < 4; ++kt)
        #pragma unroll
        for (int r = 0; r < 4; ++r) {
          const float p = exp2f(st[kt][r] - mnew);
          psum += p;
          pb[kt * 4 + r] = f2bf(p);
        }
      lrun += psum;

      // pack P^T frags: element j of k-group gk = key gk*32 + 16*(j>>2) + lg*4 + (j&3)
      s16x8 pf[2];
      #pragma unroll
      for (int gk = 0; gk < 2; ++gk)
        #pragma unroll
        for (int j = 0; j < 8; ++j)
          pf[gk][j] = (short)pb[(gk * 2 + (j >> 2)) * 4 + (j & 3)];

      // PV: yt[n] += V^T_frag * pf[gk]; V^T frag elem j = V[key gk*32+16*(j>>2)+lg*4+(j&3)][n*16+lr]
      #pragma unroll
      for (int gk = 0; gk < 2; ++gk) {
        s16x4 va[8], vb2[8];
        #pragma unroll
        for (int n = 0; n < 8; ++n) {
          // subtile S = (kq = gk*8+lg)*8 + (dq = n); lane addr = S*128 + lr*8 bytes
          const uint32_t a0 = vbase + ((uint32_t)((gk * 8 + lg) * 8 + n)) * 128 + (uint32_t)lr * 8;
          asm volatile("ds_read_b64_tr_b16 %0, %1" : "=v"(va[n])  : "v"(a0));
          asm volatile("ds_read_b64_tr_b16 %0, %1" : "=v"(vb2[n]) : "v"(a0 + 4096));
        }
        asm volatile("s_waitcnt lgkmcnt(0)" ::: "memory");
        __builtin_amdgcn_sched_barrier(0);
        __builtin_amdgcn_s_setprio(1);
        #pragma unroll
        for (int n = 0; n < 8; ++n) {
          s16x8 vf;
          vf[0] = va[n][0];  vf[1] = va[n][1];  vf[2] = va[n][2];  vf[3] = va[n][3];
          vf[4] = vb2[n][0]; vf[5] = vb2[n][1]; vf[6] = vb2[n][2]; vf[7] = vb2[n][3];
          yt[n] = __builtin_amdgcn_mfma_f32_16x16x32_bf16(vf, pf[gk], yt[n], 0, 0, 0);
        }
        __builtin_amdgcn_s_setprio(0);
      }
      __syncthreads();
    }

    // finalize: reduce l across the 4 lane-groups, scale, write att row
    lrun += __shfl_xor(lrun, 16);
    lrun += __shfl_xor(lrun, 32);
    const float inv = 1.f / lrun;
    unsigned short* yrow = Yatt + (size_t)(b * NT + q0w + lr) * NC + h * HD;
    #pragma unroll
    for (int n = 0; n < 8; ++n)
      #pragma unroll
      for (int r = 0; r < 4; ++r)
        yrow[n * 16 + lg * 4 + r] = f2bf(yt[n][r] * inv);
  }
}

extern "C" void kernel_launch(void* const* d_in, const int* in_sizes, int n_in,
                              void* d_out, int out_size, void* d_ws, size_t ws_size,
                              hipStream_t stream) {
  (void)in_sizes; (void)n_in; (void)out_size; (void)ws_size;
  const float* x     = (const float*)d_in[0];
  const float* Wqkv  = (const float*)d_in[1];
  const float* bqkv  = (const float*)d_in[2];
  const float* Wproj = (const float*)d_in[3];
  const float* bproj = (const float*)d_in[4];
  float* out = (float*)d_out;
  char* ws = (char*)d_ws;

  // workspace layout (160 MB total)
  unsigned short* xb     = (unsigned short*)(ws);               // 32MB  [BT][NC] bf16
  unsigned short* WqkvT  = (unsigned short*)(ws + 33554432);    // 24MB  [6144][2048]
  unsigned short* WprojT = (unsigned short*)(ws + 58720256);    // 8MB   [2048][2048]
  unsigned short* Qb     = (unsigned short*)(ws + 67108864);    // 32MB  [BH][T][D]
  unsigned short* Kb     = (unsigned short*)(ws + 100663296);   // 32MB
  unsigned short* Vb     = (unsigned short*)(ws + 134217728);   // 32MB
  unsigned short* att    = xb;  // reuse (xb dead after GEMM1)

  k_convert_bf16<<<dim3(8192), dim3(256), 0, stream>>>(x, xb, BT * NC / 8);
  k_transpose_bf16<<<dim3(96, 32), dim3(256), 0, stream>>>(Wqkv, WqkvT, NC, 3 * NC);
  k_transpose_bf16<<<dim3(32, 32), dim3(256), 0, stream>>>(Wproj, WprojT, NC, NC);
  k_gemm256<0><<<dim3(24, 32), dim3(512), 0, stream>>>(xb, WqkvT, bqkv, nullptr, Qb, Kb, Vb, BT, 3 * NC, NC);
  k_rope<<<dim3(32768), dim3(256), 0, stream>>>(Qb, Kb);
  k_attn<<<dim3(64, 16), dim3(256), 0, stream>>>(Qb, Kb, Vb, att);
  k_gemm256<1><<<dim3(8, 32), dim3(512), 0, stream>>>(att, WprojT, bproj, out, nullptr, nullptr, nullptr, BT, NC, NC);
}

// Round 6
// 468.236 us; speedup vs baseline: 1.5950x; 1.0056x over previous
//
#include <hip/hip_runtime.h>
#include <hip/hip_bf16.h>
#include <stdint.h>
#include <math.h>

// Problem constants
#define NB 4
#define NT 2048
#define NC 2048
#define NH 16
#define HD 128
#define BT (NB*NT)   // 8192

typedef __attribute__((ext_vector_type(8))) short s16x8;
typedef __attribute__((ext_vector_type(4))) short s16x4;
typedef __attribute__((ext_vector_type(4))) float f32x4;

typedef __attribute__((address_space(1))) void as1_void;
typedef __attribute__((address_space(3))) void as3_void;

#define CFENCE asm volatile("" ::: "memory")

static __device__ __forceinline__ unsigned short f2bf(float f) {
  union { float f; uint32_t u; } v; v.f = f;
  return (unsigned short)((v.u + 0x7fffu + ((v.u >> 16) & 1u)) >> 16);
}
static __device__ __forceinline__ float bf2f(unsigned short u) {
  union { uint32_t u; float f; } v; v.u = ((uint32_t)u) << 16;
  return v.f;
}
static __device__ __forceinline__ void async16(unsigned short* lds, const unsigned short* g) {
  __builtin_amdgcn_global_load_lds((as1_void*)g, (as3_void*)lds, 16, 0, 0);
}
static __device__ __forceinline__ uint32_t lds_off(void* p) {
  return (uint32_t)(size_t)(as3_void*)p;
}

// ---------------- fp32 -> bf16 convert (vectorized, 8 elems/thread) ----------------
__global__ void k_convert_bf16(const float* __restrict__ in, unsigned short* __restrict__ out, int n8) {
  int i = blockIdx.x * blockDim.x + threadIdx.x;
  if (i >= n8) return;
  const float4* p = (const float4*)in + (size_t)i * 2;
  float4 a = p[0], b = p[1];
  union { unsigned short s[8]; uint4 u; } o;
  o.s[0] = f2bf(a.x); o.s[1] = f2bf(a.y); o.s[2] = f2bf(a.z); o.s[3] = f2bf(a.w);
  o.s[4] = f2bf(b.x); o.s[5] = f2bf(b.y); o.s[6] = f2bf(b.z); o.s[7] = f2bf(b.w);
  ((uint4*)out)[i] = o.u;
}

// ---------------- transpose + convert: W [K][N] fp32 -> WT [N][K] bf16 ----------------
__global__ void k_transpose_bf16(const float* __restrict__ W, unsigned short* __restrict__ WT, int K, int N) {
  __shared__ unsigned short tile[64][65];
  const int k0 = blockIdx.y * 64, n0 = blockIdx.x * 64;
  const int t = threadIdx.x;
  const int jj = t & 63, base_i = t >> 6;
  #pragma unroll
  for (int p = 0; p < 16; ++p) {
    int i = p * 4 + base_i;
    tile[i][jj] = f2bf(W[(size_t)(k0 + i) * N + n0 + jj]);
  }
  __syncthreads();
  #pragma unroll
  for (int p = 0; p < 16; ++p) {
    int j = p * 4 + base_i;
    WT[(size_t)(n0 + j) * K + k0 + jj] = tile[jj][j];
  }
}

// ---------------- RoPE in-place on Q,K [BH][T][D]; fold scale*log2e into Q ----------------
__global__ void k_rope(unsigned short* __restrict__ Q, unsigned short* __restrict__ Kb) {
  int idx = blockIdx.x * 256 + threadIdx.x;  // over BH*T*64
  int d = idx & 63;
  int tpos = (idx >> 6) & (NT - 1);
  int bh = idx >> 17;
  size_t o = ((size_t)bh * NT + tpos) * HD + d;
  float invf = exp2f(-(float)d * 0.2076205059304602f);  // log2(10000)/64
  float ang = (float)tpos * invf;
  float s, c;
  sincosf(ang, &s, &c);
  float q1 = bf2f(Q[o]),  q2 = bf2f(Q[o + 64]);
  float k1 = bf2f(Kb[o]), k2 = bf2f(Kb[o + 64]);
  const float qs = 0.08838834764831845f * 1.4426950408889634f;  // (1/sqrt(128))*log2e
  Q[o]       = f2bf((q1 * c - q2 * s) * qs);
  Q[o + 64]  = f2bf((q2 * c + q1 * s) * qs);
  Kb[o]      = f2bf(k1 * c - k2 * s);
  Kb[o + 64] = f2bf(k2 * c + k1 * s);
}

// ---------------- GEMM 256x256, BK=64, 512 thr / 8 waves (2Mx4N) ----------------
// 4-phase counted-vmcnt schedule (T3+T4+T5). LDS units are K-SLICES (kk half of
// A and B), so all waves can compute kk=0 before kk=1 lands -> vmcnt never 0.
// Sync ledger (per-thread load issue order; 2 loads/phase):
//   prologue: U(0,0)A U(0,0)B U(0,1)A U(0,1)B -> vmcnt(4) [U(0,0) ready], barrier
//   tile tau (buf=tau&1, staging U(tau+1,*) into buf^1):
//     q0: stage A(kk0) | read kk0 mi0-3 + B kk0 | 16 MFMA | barrier
//     q1: stage B(kk0) | read kk0 mi4-7         | 16 MFMA | vmcnt(4)=U(tau,1) ready | barrier
//     q2: stage A(kk1) | read kk1 mi0-3 + B kk1 | 16 MFMA | barrier
//     q3: stage B(kk1) | read kk1 mi4-7         | 16 MFMA | vmcnt(4)=U(tau+1,0) ready | barrier
// vmcnt BEFORE barrier => barrier join guarantees all waves' staged portions landed.
// LDS layout per unit [128 lines][8 slots of 16B]: line l holds rows {2l,2l+1};
// slot phys = ((rowparity<<2)|kchunk) ^ (l&7)  (max 2-way bank conflict = free).
// global_load_lds dest stays linear; source pre-swizzled accordingly.
template<int MODE>
__global__ __launch_bounds__(512, 2)
void k_gemm8p(const unsigned short* __restrict__ A,
              const unsigned short* __restrict__ Bt,
              const float* __restrict__ bias,
              float* __restrict__ OutF,
              unsigned short* __restrict__ Qd,
              unsigned short* __restrict__ Kd,
              unsigned short* __restrict__ Vd,
              int M, int N, int K)
{
  __shared__ __align__(16) unsigned short Al[2][2][8192];
  __shared__ __align__(16) unsigned short Bl[2][2][8192];
  const int t = threadIdx.x;
  const int l = t & 63;
  const int wv = t >> 6;
  const int wm = wv >> 2, wn = wv & 3;     // 2 x 4 wave grid; wave tile 128x64
  const int bm = blockIdx.y * 256, bn = blockIdx.x * 256;
  const int lr = l & 15, lg = l >> 4;
  const int wbase = (t & 448);             // wave-uniform thread base

  f32x4 acc[8][4];
  #pragma unroll
  for (int i = 0; i < 8; ++i)
    #pragma unroll
    for (int j = 0; j < 4; ++j)
      acc[i][j] = f32x4{0.f, 0.f, 0.f, 0.f};

  // per-thread pre-swizzled global (row, kchunk) for stage loads i=0,1
  int srow0, sc0, srow1, sc1;
  {
    int n = t;            int lq = n >> 3, v = (n & 7) ^ (lq & 7);
    srow0 = 2 * lq + (v >> 2); sc0 = v & 3;
  }
  {
    int n = 512 + t;      int lq = n >> 3, v = (n & 7) ^ (lq & 7);
    srow1 = 2 * lq + (v >> 2); sc1 = v & 3;
  }

  auto stageA = [&](int buf, int kk, int k0) {
    async16(&Al[buf][kk][(0 * 512 + wbase) * 8], &A[(size_t)(bm + srow0) * K + k0 + kk * 32 + sc0 * 8]);
    async16(&Al[buf][kk][(1 * 512 + wbase) * 8], &A[(size_t)(bm + srow1) * K + k0 + kk * 32 + sc1 * 8]);
  };
  auto stageB = [&](int buf, int kk, int k0) {
    async16(&Bl[buf][kk][(0 * 512 + wbase) * 8], &Bt[(size_t)(bn + srow0) * K + k0 + kk * 32 + sc0 * 8]);
    async16(&Bl[buf][kk][(1 * 512 + wbase) * 8], &Bt[(size_t)(bn + srow1) * K + k0 + kk * 32 + sc1 * 8]);
  };
  auto lda = [&](int buf, int kk, int mi) -> s16x8 {
    const int row = wm * 128 + mi * 16 + lr;
    const int lq = row >> 1;
    const int phys = (((row & 1) << 2) | lg) ^ (lq & 7);
    return *(const s16x8*)&Al[buf][kk][lq * 64 + phys * 8];
  };
  auto ldb = [&](int buf, int kk, int ni) -> s16x8 {
    const int row = wn * 64 + ni * 16 + lr;
    const int lq = row >> 1;
    const int phys = (((row & 1) << 2) | lg) ^ (lq & 7);
    return *(const s16x8*)&Bl[buf][kk][lq * 64 + phys * 8];
  };

  // prologue
  stageA(0, 0, 0); stageB(0, 0, 0); stageA(0, 1, 0); stageB(0, 1, 0);
  asm volatile("s_waitcnt vmcnt(4)" ::: "memory");
  CFENCE; __builtin_amdgcn_s_barrier(); CFENCE;

  const int nkt = K >> 6;
  #pragma unroll 1
  for (int tau = 0; tau < nkt; ++tau) {
    const int buf = tau & 1, nbuf = buf ^ 1;
    const int k0n = (tau + 1 < nkt) ? ((tau + 1) << 6) : 0;  // dummy stage keeps vmcnt ledger aligned
    s16x8 af[4], bfr[4];

    // ---- q0: kk=0, mi 0-3 (+B kk0) ----
    stageA(nbuf, 0, k0n);
    #pragma unroll
    for (int i = 0; i < 4; ++i) af[i] = lda(buf, 0, i);
    #pragma unroll
    for (int j = 0; j < 4; ++j) bfr[j] = ldb(buf, 0, j);
    __builtin_amdgcn_s_setprio(1);
    #pragma unroll
    for (int i = 0; i < 4; ++i)
      #pragma unroll
      for (int j = 0; j < 4; ++j)
        acc[i][j] = __builtin_amdgcn_mfma_f32_16x16x32_bf16(af[i], bfr[j], acc[i][j], 0, 0, 0);
    __builtin_amdgcn_s_setprio(0);
    CFENCE; __builtin_amdgcn_s_barrier(); CFENCE;

    // ---- q1: kk=0, mi 4-7 ----
    stageB(nbuf, 0, k0n);
    #pragma unroll
    for (int i = 0; i < 4; ++i) af[i] = lda(buf, 0, 4 + i);
    __builtin_amdgcn_s_setprio(1);
    #pragma unroll
    for (int i = 0; i < 4; ++i)
      #pragma unroll
      for (int j = 0; j < 4; ++j)
        acc[4 + i][j] = __builtin_amdgcn_mfma_f32_16x16x32_bf16(af[i], bfr[j], acc[4 + i][j], 0, 0, 0);
    __builtin_amdgcn_s_setprio(0);
    asm volatile("s_waitcnt vmcnt(4)" ::: "memory");   // U(tau,1) ready
    CFENCE; __builtin_amdgcn_s_barrier(); CFENCE;

    // ---- q2: kk=1, mi 0-3 (+B kk1) ----
    stageA(nbuf, 1, k0n);
    #pragma unroll
    for (int i = 0; i < 4; ++i) af[i] = lda(buf, 1, i);
    #pragma unroll
    for (int j = 0; j < 4; ++j) bfr[j] = ldb(buf, 1, j);
    __builtin_amdgcn_s_setprio(1);
    #pragma unroll
    for (int i = 0; i < 4; ++i)
      #pragma unroll
      for (int j = 0; j < 4; ++j)
        acc[i][j] = __builtin_amdgcn_mfma_f32_16x16x32_bf16(af[i], bfr[j], acc[i][j], 0, 0, 0);
    __builtin_amdgcn_s_setprio(0);
    CFENCE; __builtin_amdgcn_s_barrier(); CFENCE;

    // ---- q3: kk=1, mi 4-7 ----
    stageB(nbuf, 1, k0n);
    #pragma unroll
    for (int i = 0; i < 4; ++i) af[i] = lda(buf, 1, 4 + i);
    __builtin_amdgcn_s_setprio(1);
    #pragma unroll
    for (int i = 0; i < 4; ++i)
      #pragma unroll
      for (int j = 0; j < 4; ++j)
        acc[4 + i][j] = __builtin_amdgcn_mfma_f32_16x16x32_bf16(af[i], bfr[j], acc[4 + i][j], 0, 0, 0);
    __builtin_amdgcn_s_setprio(0);
    asm volatile("s_waitcnt vmcnt(4)" ::: "memory");   // U(tau+1,0) ready
    CFENCE; __builtin_amdgcn_s_barrier(); CFENCE;
  }

  // epilogue; C/D layout: col = lane&15, row = (lane>>4)*4 + reg  [m89-verified]
  #pragma unroll
  for (int mi = 0; mi < 8; ++mi) {
    #pragma unroll
    for (int ni = 0; ni < 4; ++ni) {
      const int col = bn + wn * 64 + ni * 16 + lr;
      const float bv = bias[col];
      #pragma unroll
      for (int r = 0; r < 4; ++r) {
        const int row = bm + wm * 128 + mi * 16 + lg * 4 + r;
        const float v = acc[mi][ni][r] + bv;
        if (MODE == 1) {
          OutF[(size_t)row * N + col] = v;
        } else {
          const int which = col >> 11;         // 0=q 1=k 2=v (uniform per block: 2048%256==0)
          const int cc = col & 2047;
          const int h = cc >> 7, d = cc & 127;
          const int b = row >> 11, tp = row & 2047;
          unsigned short* dst = (which == 0) ? Qd : (which == 1 ? Kd : Vd);
          dst[(((size_t)(b * NH + h)) * NT + tp) * HD + d] = f2bf(v);
        }
      }
    }
  }
}

// ---------------- flash attention: 4 waves x 16 q-rows, KV tile 64 ----------------
// Causal-balanced: grid = (bh 64, pair 16); block processes q-tiles {pair, 31-pair}
// sequentially -> constant 33 kv-iters per block. Grid layout puts all 16 blocks
// of head bh at linear IDs == bh (mod 64) -> same XCD (round-robin mod 8), so a
// head's K/V stream stays in one L2.
// swapped S^T = mfma(K, Q): lane owns q = lane&15; keys live at (lane>>4)*4+reg.
// PV: y^T = mfma(V^T via ds_read_b64_tr_b16 from subtiled V_lds, P^T from regs).
// tr_read semantics: each lane reads contiguous 8B at its own addr; the 16-lane
// group's 128B window is a row-major [4][16] bf16 matrix, lane l gets column l&15.
__global__ __launch_bounds__(256, 2)
void k_attn(const unsigned short* __restrict__ Q,
            const unsigned short* __restrict__ Kg,
            const unsigned short* __restrict__ Vg,
            unsigned short* __restrict__ Yatt)   // att [BT][NC] bf16
{
  __shared__ __align__(16) unsigned short Kl[64 * 128];  // [key][d], 16B-chunk-swizzled
  __shared__ __align__(16) unsigned short Vl[64 * 128];  // subtiled [key/4][d/16][4][16]
  const int bh = blockIdx.x;          // 0..63  (x-major => same-head blocks same XCD)
  const int pair = blockIdx.y;        // 0..15
  const int b = bh >> 4, h = bh & 15;
  const int t = threadIdx.x, l = t & 63, wv = t >> 6;
  const int lr = l & 15, lg = l >> 4;
  const size_t hoff = (size_t)bh * NT * HD;
  const unsigned short* Qh = Q + hoff;
  const unsigned short* Kh = Kg + hoff;
  const unsigned short* Vh = Vg + hoff;
  const uint32_t vbase = lds_off(Vl);

  #pragma unroll 1
  for (int rep = 0; rep < 2; ++rep) {
    const int qb = rep ? (31 - pair) : pair;
    const int q0w = qb * 64 + wv * 16;
    const int qrow = q0w + lr;

    s16x8 qf[4];  // Q[qrow][m*32 + lg*8 .. +8]
    #pragma unroll
    for (int m = 0; m < 4; ++m)
      qf[m] = *(const s16x8*)(Qh + (size_t)qrow * HD + m * 32 + lg * 8);

    f32x4 yt[8];  // y^T: 8 d-tiles of 16; lane: q=lr, d = n*16 + lg*4 + r
    #pragma unroll
    for (int n = 0; n < 8; ++n) yt[n] = f32x4{0.f, 0.f, 0.f, 0.f};
    float mrun = -1e30f, lrun = 0.f;

    const int nkv = qb + 1;
    for (int kv = 0; kv < nkv; ++kv) {
      const int kv0 = kv * 64;
      #pragma unroll
      for (int i = 0; i < 4; ++i) {
        const int Cc = i * 256 + t;
        {  // K tile: row-major [64][128], 16B chunks swizzled with (row&7)
          const int krow = Cc >> 4;
          const int kc = (Cc & 15) ^ (krow & 7);
          async16(&Kl[(i * 256 + (t & 192)) * 8], &Kh[(size_t)(kv0 + krow) * HD + kc * 8]);
        }
        {  // V tile: subtile S = kq*8+dq holds [4 keys][16 d] row-major
          const int S = Cc >> 3, c8 = Cc & 7;
          const int kq = S >> 3, dq = S & 7;
          const int vk = kq * 4 + (c8 >> 1), vd = dq * 16 + (c8 & 1) * 8;
          async16(&Vl[(i * 256 + (t & 192)) * 8], &Vh[(size_t)(kv0 + vk) * HD + vd]);
        }
      }
      __syncthreads();

      // S^T tiles: 4 key-tiles of 16, k-dim = d (4 chunks of 32)
      f32x4 st[4];
      __builtin_amdgcn_s_setprio(1);
      #pragma unroll
      for (int kt = 0; kt < 4; ++kt) {
        f32x4 a = f32x4{0.f, 0.f, 0.f, 0.f};
        const int krow = kt * 16 + lr;
        #pragma unroll
        for (int m = 0; m < 4; ++m) {
          const int ch = (m * 4 + lg) ^ (krow & 7);
          s16x8 kf = *(const s16x8*)&Kl[krow * 128 + ch * 8];
          a = __builtin_amdgcn_mfma_f32_16x16x32_bf16(kf, qf[m], a, 0, 0, 0);
        }
        st[kt] = a;
      }
      __builtin_amdgcn_s_setprio(0);

      // causal mask (only needed near diagonal)
      if (kv0 + 63 > q0w) {
        #pragma unroll
        for (int kt = 0; kt < 4; ++kt)
          #pragma unroll
          for (int r = 0; r < 4; ++r) {
            const int key = kv0 + kt * 16 + lg * 4 + r;
            if (key > qrow) st[kt][r] = -3.0e38f;
          }
      }

      // online softmax (S already scaled by 1/sqrt(D)*log2e via Q)
      float tm = -3.0e38f;
      #pragma unroll
      for (int kt = 0; kt < 4; ++kt)
        #pragma unroll
        for (int r = 0; r < 4; ++r) tm = fmaxf(tm, st[kt][r]);
      tm = fmaxf(tm, __shfl_xor(tm, 16));
      tm = fmaxf(tm, __shfl_xor(tm, 32));
      const float mnew = fmaxf(mrun, tm);
      const float fsc = exp2f(mrun - mnew);
      mrun = mnew;
      lrun *= fsc;
      #pragma unroll
      for (int n = 0; n < 8; ++n)
        #pragma unroll
        for (int r = 0; r < 4; ++r) yt[n][r] *= fsc;

      unsigned short pb[16];
      float psum = 0.f;
      #pragma unroll
      for (int kt = 0; kt < 4; ++kt)
        #pragma unroll
        for (int r = 0; r < 4; ++r) {
          const float p = exp2f(st[kt][r] - mnew);
          psum += p;
          pb[kt * 4 + r] = f2bf(p);
        }
      lrun += psum;

      // pack P^T frags: element j of k-group gk = key gk*32 + 16*(j>>2) + lg*4 + (j&3)
      s16x8 pf[2];
      #pragma unroll
      for (int gk = 0; gk < 2; ++gk)
        #pragma unroll
        for (int j = 0; j < 8; ++j)
          pf[gk][j] = (short)pb[(gk * 2 + (j >> 2)) * 4 + (j & 3)];

      // PV: yt[n] += V^T_frag * pf[gk]; V^T frag elem j = V[key gk*32+16*(j>>2)+lg*4+(j&3)][n*16+lr]
      #pragma unroll
      for (int gk = 0; gk < 2; ++gk) {
        s16x4 va[8], vb2[8];
        #pragma unroll
        for (int n = 0; n < 8; ++n) {
          // subtile S = (kq = gk*8+lg)*8 + (dq = n); lane addr = S*128 + lr*8 bytes
          const uint32_t a0 = vbase + ((uint32_t)((gk * 8 + lg) * 8 + n)) * 128 + (uint32_t)lr * 8;
          asm volatile("ds_read_b64_tr_b16 %0, %1" : "=v"(va[n])  : "v"(a0));
          asm volatile("ds_read_b64_tr_b16 %0, %1" : "=v"(vb2[n]) : "v"(a0 + 4096));
        }
        asm volatile("s_waitcnt lgkmcnt(0)" ::: "memory");
        __builtin_amdgcn_sched_barrier(0);
        __builtin_amdgcn_s_setprio(1);
        #pragma unroll
        for (int n = 0; n < 8; ++n) {
          s16x8 vf;
          vf[0] = va[n][0];  vf[1] = va[n][1];  vf[2] = va[n][2];  vf[3] = va[n][3];
          vf[4] = vb2[n][0]; vf[5] = vb2[n][1]; vf[6] = vb2[n][2]; vf[7] = vb2[n][3];
          yt[n] = __builtin_amdgcn_mfma_f32_16x16x32_bf16(vf, pf[gk], yt[n], 0, 0, 0);
        }
        __builtin_amdgcn_s_setprio(0);
      }
      __syncthreads();
    }

    // finalize: reduce l across the 4 lane-groups, scale, write att row
    lrun += __shfl_xor(lrun, 16);
    lrun += __shfl_xor(lrun, 32);
    const float inv = 1.f / lrun;
    unsigned short* yrow = Yatt + (size_t)(b * NT + q0w + lr) * NC + h * HD;
    #pragma unroll
    for (int n = 0; n < 8; ++n)
      #pragma unroll
      for (int r = 0; r < 4; ++r)
        yrow[n * 16 + lg * 4 + r] = f2bf(yt[n][r] * inv);
  }
}

extern "C" void kernel_launch(void* const* d_in, const int* in_sizes, int n_in,
                              void* d_out, int out_size, void* d_ws, size_t ws_size,
                              hipStream_t stream) {
  (void)in_sizes; (void)n_in; (void)out_size; (void)ws_size;
  const float* x     = (const float*)d_in[0];
  const float* Wqkv  = (const float*)d_in[1];
  const float* bqkv  = (const float*)d_in[2];
  const float* Wproj = (const float*)d_in[3];
  const float* bproj = (const float*)d_in[4];
  float* out = (float*)d_out;
  char* ws = (char*)d_ws;

  // workspace layout (160 MB total)
  unsigned short* xb     = (unsigned short*)(ws);               // 32MB  [BT][NC] bf16
  unsigned short* WqkvT  = (unsigned short*)(ws + 33554432);    // 24MB  [6144][2048]
  unsigned short* WprojT = (unsigned short*)(ws + 58720256);    // 8MB   [2048][2048]
  unsigned short* Qb     = (unsigned short*)(ws + 67108864);    // 32MB  [BH][T][D]
  unsigned short* Kb     = (unsigned short*)(ws + 100663296);   // 32MB
  unsigned short* Vb     = (unsigned short*)(ws + 134217728);   // 32MB
  unsigned short* att    = xb;  // reuse (xb dead after GEMM1)

  k_convert_bf16<<<dim3(8192), dim3(256), 0, stream>>>(x, xb, BT * NC / 8);
  k_transpose_bf16<<<dim3(96, 32), dim3(256), 0, stream>>>(Wqkv, WqkvT, NC, 3 * NC);
  k_transpose_bf16<<<dim3(32, 32), dim3(256), 0, stream>>>(Wproj, WprojT, NC, NC);
  k_gemm8p<0><<<dim3(24, 32), dim3(512), 0, stream>>>(xb, WqkvT, bqkv, nullptr, Qb, Kb, Vb, BT, 3 * NC, NC);
  k_rope<<<dim3(32768), dim3(256), 0, stream>>>(Qb, Kb);
  k_attn<<<dim3(64, 16), dim3(256), 0, stream>>>(Qb, Kb, Vb, att);
  k_gemm8p<1><<<dim3(8, 32), dim3(512), 0, stream>>>(att, WprojT, bproj, out, nullptr, nullptr, nullptr, BT, NC, NC);
}

// Round 7
// 446.601 us; speedup vs baseline: 1.6723x; 1.0484x over previous
//
#include <hip/hip_runtime.h>
#include <hip/hip_bf16.h>
#include <stdint.h>
#include <math.h>

// Problem constants
#define NB 4
#define NT 2048
#define NC 2048
#define NH 16
#define HD 128
#define BT (NB*NT)   // 8192

typedef __attribute__((ext_vector_type(8))) short s16x8;
typedef __attribute__((ext_vector_type(4))) short s16x4;
typedef __attribute__((ext_vector_type(4))) float f32x4;

typedef __attribute__((address_space(1))) void as1_void;
typedef __attribute__((address_space(3))) void as3_void;

static __device__ __forceinline__ unsigned short f2bf(float f) {
  union { float f; uint32_t u; } v; v.f = f;
  return (unsigned short)((v.u + 0x7fffu + ((v.u >> 16) & 1u)) >> 16);
}
static __device__ __forceinline__ float bf2f(unsigned short u) {
  union { uint32_t u; float f; } v; v.u = ((uint32_t)u) << 16;
  return v.f;
}
static __device__ __forceinline__ void async16(unsigned short* lds, const unsigned short* g) {
  __builtin_amdgcn_global_load_lds((as1_void*)g, (as3_void*)lds, 16, 0, 0);
}
static __device__ __forceinline__ uint32_t lds_off(void* p) {
  return (uint32_t)(size_t)(as3_void*)p;
}

// ---------------- fp32 -> bf16 convert (vectorized, 8 elems/thread) ----------------
__global__ void k_convert_bf16(const float* __restrict__ in, unsigned short* __restrict__ out, int n8) {
  int i = blockIdx.x * blockDim.x + threadIdx.x;
  if (i >= n8) return;
  const float4* p = (const float4*)in + (size_t)i * 2;
  float4 a = p[0], b = p[1];
  union { unsigned short s[8]; uint4 u; } o;
  o.s[0] = f2bf(a.x); o.s[1] = f2bf(a.y); o.s[2] = f2bf(a.z); o.s[3] = f2bf(a.w);
  o.s[4] = f2bf(b.x); o.s[5] = f2bf(b.y); o.s[6] = f2bf(b.z); o.s[7] = f2bf(b.w);
  ((uint4*)out)[i] = o.u;
}

// ---------------- transpose + convert: W [K][N] fp32 -> WT [N][K] bf16 ----------------
__global__ void k_transpose_bf16(const float* __restrict__ W, unsigned short* __restrict__ WT, int K, int N) {
  __shared__ unsigned short tile[64][65];
  const int k0 = blockIdx.y * 64, n0 = blockIdx.x * 64;
  const int t = threadIdx.x;
  const int jj = t & 63, base_i = t >> 6;
  #pragma unroll
  for (int p = 0; p < 16; ++p) {
    int i = p * 4 + base_i;
    tile[i][jj] = f2bf(W[(size_t)(k0 + i) * N + n0 + jj]);
  }
  __syncthreads();
  #pragma unroll
  for (int p = 0; p < 16; ++p) {
    int j = p * 4 + base_i;
    WT[(size_t)(n0 + j) * K + k0 + jj] = tile[jj][j];
  }
}

// ---------------- RoPE in-place on Q,K [BH][T][D]; fold scale*log2e into Q ----------------
__global__ void k_rope(unsigned short* __restrict__ Q, unsigned short* __restrict__ Kb) {
  int idx = blockIdx.x * 256 + threadIdx.x;  // over BH*T*64
  int d = idx & 63;
  int tpos = (idx >> 6) & (NT - 1);
  int bh = idx >> 17;
  size_t o = ((size_t)bh * NT + tpos) * HD + d;
  float invf = exp2f(-(float)d * 0.2076205059304602f);  // log2(10000)/64
  float ang = (float)tpos * invf;
  float s, c;
  sincosf(ang, &s, &c);
  float q1 = bf2f(Q[o]),  q2 = bf2f(Q[o + 64]);
  float k1 = bf2f(Kb[o]), k2 = bf2f(Kb[o + 64]);
  const float qs = 0.08838834764831845f * 1.4426950408889634f;  // (1/sqrt(128))*log2e
  Q[o]       = f2bf((q1 * c - q2 * s) * qs);
  Q[o + 64]  = f2bf((q2 * c + q1 * s) * qs);
  Kb[o]      = f2bf(k1 * c - k2 * s);
  Kb[o + 64] = f2bf(k2 * c + k1 * s);
}

// ---------------- GEMM 256x128 block, BK=64, 256 thr / 4 waves (2Mx2N) ----------------
// Wave tile 128x64 -> 42.7 FLOP per LDS-byte (vs 32 at 64x64) while LDS = 48 KiB
// keeps 2 blocks/CU (the r4-proven cross-block overlap regime). 2-phase
// __syncthreads structure, r4 chunk-XOR swizzle (measured 0 bank conflicts):
// LDS 16B-chunk (row, c) holds logical k-chunk (c ^ (row&7)); linear gload_lds dest,
// pre-swizzled global source.
// MODE 0: scatter bf16 into Q/K/V [B][H][T][D]. MODE 1: fp32 row-major out.
template<int MODE>
__global__ __launch_bounds__(256, 2)
void k_gemm_bt2(const unsigned short* __restrict__ A,
                const unsigned short* __restrict__ Bt,
                const float* __restrict__ bias,
                float* __restrict__ OutF,
                unsigned short* __restrict__ Qd,
                unsigned short* __restrict__ Kd,
                unsigned short* __restrict__ Vd,
                int M, int N, int K)
{
  __shared__ __align__(16) unsigned short Al[256 * 64];
  __shared__ __align__(16) unsigned short Bl[128 * 64];
  const int t = threadIdx.x;
  const int l = t & 63;
  const int wv = t >> 6;
  const int wm = wv >> 1, wn = wv & 1;     // 2 x 2 wave grid; wave tile 128x64
  const int bm = blockIdx.y * 256, bn = blockIdx.x * 128;
  const int lr = l & 15, lg = l >> 4;

  f32x4 acc[8][4];
  #pragma unroll
  for (int i = 0; i < 8; ++i)
    #pragma unroll
    for (int j = 0; j < 4; ++j)
      acc[i][j] = f32x4{0.f, 0.f, 0.f, 0.f};

  for (int k0 = 0; k0 < K; k0 += 64) {
    // stage A 256x64 (2048 chunks, 8 rounds) + B 128x64 (1024 chunks, 4 rounds)
    #pragma unroll
    for (int i = 0; i < 8; ++i) {
      const int Cc = i * 256 + t;          // 16B chunk id
      const int row = Cc >> 3;
      const int kc = (Cc & 7) ^ (row & 7);
      async16(&Al[(i * 256 + (t & 192)) * 8], &A[(size_t)(bm + row) * K + k0 + kc * 8]);
    }
    #pragma unroll
    for (int i = 0; i < 4; ++i) {
      const int Cc = i * 256 + t;
      const int row = Cc >> 3;
      const int kc = (Cc & 7) ^ (row & 7);
      async16(&Bl[(i * 256 + (t & 192)) * 8], &Bt[(size_t)(bn + row) * K + k0 + kc * 8]);
    }
    __syncthreads();
    #pragma unroll
    for (int kk = 0; kk < 2; ++kk) {
      s16x8 af[8], bfr[4];
      #pragma unroll
      for (int mi = 0; mi < 8; ++mi) {
        const int row = wm * 128 + mi * 16 + lr;
        const int ch = (kk * 4 + lg) ^ (row & 7);
        af[mi] = *(const s16x8*)&Al[row * 64 + ch * 8];
      }
      #pragma unroll
      for (int ni = 0; ni < 4; ++ni) {
        const int row = wn * 64 + ni * 16 + lr;
        const int ch = (kk * 4 + lg) ^ (row & 7);
        bfr[ni] = *(const s16x8*)&Bl[row * 64 + ch * 8];
      }
      __builtin_amdgcn_s_setprio(1);
      #pragma unroll
      for (int mi = 0; mi < 8; ++mi)
        #pragma unroll
        for (int ni = 0; ni < 4; ++ni)
          acc[mi][ni] = __builtin_amdgcn_mfma_f32_16x16x32_bf16(af[mi], bfr[ni], acc[mi][ni], 0, 0, 0);
      __builtin_amdgcn_s_setprio(0);
    }
    __syncthreads();
  }

  // epilogue; C/D layout: col = lane&15, row = (lane>>4)*4 + reg  [m89-verified]
  #pragma unroll
  for (int mi = 0; mi < 8; ++mi) {
    #pragma unroll
    for (int ni = 0; ni < 4; ++ni) {
      const int col = bn + wn * 64 + ni * 16 + lr;
      const float bv = bias[col];
      #pragma unroll
      for (int r = 0; r < 4; ++r) {
        const int row = bm + wm * 128 + mi * 16 + lg * 4 + r;
        const float v = acc[mi][ni][r] + bv;
        if (MODE == 1) {
          OutF[(size_t)row * N + col] = v;
        } else {
          const int which = col >> 11;         // 0=q 1=k 2=v (uniform per block: 2048%128==0)
          const int cc = col & 2047;
          const int h = cc >> 7, d = cc & 127;
          const int b = row >> 11, tp = row & 2047;
          unsigned short* dst = (which == 0) ? Qd : (which == 1 ? Kd : Vd);
          dst[(((size_t)(b * NH + h)) * NT + tp) * HD + d] = f2bf(v);
        }
      }
    }
  }
}

// ---------------- flash attention: 4 waves x 16 q-rows, KV tile 64 ----------------
// Causal-balanced: grid = (bh 64, pair 16); block processes q-tiles {pair, 31-pair}
// sequentially -> constant 33 kv-iters per block. Grid layout puts all 16 blocks
// of head bh at linear IDs == bh (mod 64) -> same XCD (round-robin mod 8), so a
// head's K/V stream stays in one L2.
// swapped S^T = mfma(K, Q): lane owns q = lane&15; keys live at (lane>>4)*4+reg.
// PV: y^T = mfma(V^T via ds_read_b64_tr_b16 from subtiled V_lds, P^T from regs).
// tr_read semantics: each lane reads contiguous 8B at its own addr; the 16-lane
// group's 128B window is a row-major [4][16] bf16 matrix, lane l gets column l&15.
__global__ __launch_bounds__(256, 2)
void k_attn(const unsigned short* __restrict__ Q,
            const unsigned short* __restrict__ Kg,
            const unsigned short* __restrict__ Vg,
            unsigned short* __restrict__ Yatt)   // att [BT][NC] bf16
{
  __shared__ __align__(16) unsigned short Kl[64 * 128];  // [key][d], 16B-chunk-swizzled
  __shared__ __align__(16) unsigned short Vl[64 * 128];  // subtiled [key/4][d/16][4][16]
  const int bh = blockIdx.x;          // 0..63  (x-major => same-head blocks same XCD)
  const int pair = blockIdx.y;        // 0..15
  const int b = bh >> 4, h = bh & 15;
  const int t = threadIdx.x, l = t & 63, wv = t >> 6;
  const int lr = l & 15, lg = l >> 4;
  const size_t hoff = (size_t)bh * NT * HD;
  const unsigned short* Qh = Q + hoff;
  const unsigned short* Kh = Kg + hoff;
  const unsigned short* Vh = Vg + hoff;
  const uint32_t vbase = lds_off(Vl);

  #pragma unroll 1
  for (int rep = 0; rep < 2; ++rep) {
    const int qb = rep ? (31 - pair) : pair;
    const int q0w = qb * 64 + wv * 16;
    const int qrow = q0w + lr;

    s16x8 qf[4];  // Q[qrow][m*32 + lg*8 .. +8]
    #pragma unroll
    for (int m = 0; m < 4; ++m)
      qf[m] = *(const s16x8*)(Qh + (size_t)qrow * HD + m * 32 + lg * 8);

    f32x4 yt[8];  // y^T: 8 d-tiles of 16; lane: q=lr, d = n*16 + lg*4 + r
    #pragma unroll
    for (int n = 0; n < 8; ++n) yt[n] = f32x4{0.f, 0.f, 0.f, 0.f};
    float mrun = -1e30f, lrun = 0.f;

    const int nkv = qb + 1;
    for (int kv = 0; kv < nkv; ++kv) {
      const int kv0 = kv * 64;
      #pragma unroll
      for (int i = 0; i < 4; ++i) {
        const int Cc = i * 256 + t;
        {  // K tile: row-major [64][128], 16B chunks swizzled with (row&7)
          const int krow = Cc >> 4;
          const int kc = (Cc & 15) ^ (krow & 7);
          async16(&Kl[(i * 256 + (t & 192)) * 8], &Kh[(size_t)(kv0 + krow) * HD + kc * 8]);
        }
        {  // V tile: subtile S = kq*8+dq holds [4 keys][16 d] row-major
          const int S = Cc >> 3, c8 = Cc & 7;
          const int kq = S >> 3, dq = S & 7;
          const int vk = kq * 4 + (c8 >> 1), vd = dq * 16 + (c8 & 1) * 8;
          async16(&Vl[(i * 256 + (t & 192)) * 8], &Vh[(size_t)(kv0 + vk) * HD + vd]);
        }
      }
      __syncthreads();

      // S^T tiles: 4 key-tiles of 16, k-dim = d (4 chunks of 32)
      f32x4 st[4];
      __builtin_amdgcn_s_setprio(1);
      #pragma unroll
      for (int kt = 0; kt < 4; ++kt) {
        f32x4 a = f32x4{0.f, 0.f, 0.f, 0.f};
        const int krow = kt * 16 + lr;
        #pragma unroll
        for (int m = 0; m < 4; ++m) {
          const int ch = (m * 4 + lg) ^ (krow & 7);
          s16x8 kf = *(const s16x8*)&Kl[krow * 128 + ch * 8];
          a = __builtin_amdgcn_mfma_f32_16x16x32_bf16(kf, qf[m], a, 0, 0, 0);
        }
        st[kt] = a;
      }
      __builtin_amdgcn_s_setprio(0);

      // causal mask (only needed near diagonal)
      if (kv0 + 63 > q0w) {
        #pragma unroll
        for (int kt = 0; kt < 4; ++kt)
          #pragma unroll
          for (int r = 0; r < 4; ++r) {
            const int key = kv0 + kt * 16 + lg * 4 + r;
            if (key > qrow) st[kt][r] = -3.0e38f;
          }
      }

      // online softmax (S already scaled by 1/sqrt(D)*log2e via Q)
      float tm = -3.0e38f;
      #pragma unroll
      for (int kt = 0; kt < 4; ++kt)
        #pragma unroll
        for (int r = 0; r < 4; ++r) tm = fmaxf(tm, st[kt][r]);
      tm = fmaxf(tm, __shfl_xor(tm, 16));
      tm = fmaxf(tm, __shfl_xor(tm, 32));
      const float mnew = fmaxf(mrun, tm);
      const float fsc = exp2f(mrun - mnew);
      mrun = mnew;
      lrun *= fsc;
      #pragma unroll
      for (int n = 0; n < 8; ++n)
        #pragma unroll
        for (int r = 0; r < 4; ++r) yt[n][r] *= fsc;

      unsigned short pb[16];
      float psum = 0.f;
      #pragma unroll
      for (int kt = 0; kt < 4; ++kt)
        #pragma unroll
        for (int r = 0; r < 4; ++r) {
          const float p = exp2f(st[kt][r] - mnew);
          psum += p;
          pb[kt * 4 + r] = f2bf(p);
        }
      lrun += psum;

      // pack P^T frags: element j of k-group gk = key gk*32 + 16*(j>>2) + lg*4 + (j&3)
      s16x8 pf[2];
      #pragma unroll
      for (int gk = 0; gk < 2; ++gk)
        #pragma unroll
        for (int j = 0; j < 8; ++j)
          pf[gk][j] = (short)pb[(gk * 2 + (j >> 2)) * 4 + (j & 3)];

      // PV: yt[n] += V^T_frag * pf[gk]; V^T frag elem j = V[key gk*32+16*(j>>2)+lg*4+(j&3)][n*16+lr]
      #pragma unroll
      for (int gk = 0; gk < 2; ++gk) {
        s16x4 va[8], vb2[8];
        #pragma unroll
        for (int n = 0; n < 8; ++n) {
          // subtile S = (kq = gk*8+lg)*8 + (dq = n); lane addr = S*128 + lr*8 bytes
          const uint32_t a0 = vbase + ((uint32_t)((gk * 8 + lg) * 8 + n)) * 128 + (uint32_t)lr * 8;
          asm volatile("ds_read_b64_tr_b16 %0, %1" : "=v"(va[n])  : "v"(a0));
          asm volatile("ds_read_b64_tr_b16 %0, %1" : "=v"(vb2[n]) : "v"(a0 + 4096));
        }
        asm volatile("s_waitcnt lgkmcnt(0)" ::: "memory");
        __builtin_amdgcn_sched_barrier(0);
        __builtin_amdgcn_s_setprio(1);
        #pragma unroll
        for (int n = 0; n < 8; ++n) {
          s16x8 vf;
          vf[0] = va[n][0];  vf[1] = va[n][1];  vf[2] = va[n][2];  vf[3] = va[n][3];
          vf[4] = vb2[n][0]; vf[5] = vb2[n][1]; vf[6] = vb2[n][2]; vf[7] = vb2[n][3];
          yt[n] = __builtin_amdgcn_mfma_f32_16x16x32_bf16(vf, pf[gk], yt[n], 0, 0, 0);
        }
        __builtin_amdgcn_s_setprio(0);
      }
      __syncthreads();
    }

    // finalize: reduce l across the 4 lane-groups, scale, write att row
    lrun += __shfl_xor(lrun, 16);
    lrun += __shfl_xor(lrun, 32);
    const float inv = 1.f / lrun;
    unsigned short* yrow = Yatt + (size_t)(b * NT + q0w + lr) * NC + h * HD;
    #pragma unroll
    for (int n = 0; n < 8; ++n)
      #pragma unroll
      for (int r = 0; r < 4; ++r)
        yrow[n * 16 + lg * 4 + r] = f2bf(yt[n][r] * inv);
  }
}

extern "C" void kernel_launch(void* const* d_in, const int* in_sizes, int n_in,
                              void* d_out, int out_size, void* d_ws, size_t ws_size,
                              hipStream_t stream) {
  (void)in_sizes; (void)n_in; (void)out_size; (void)ws_size;
  const float* x     = (const float*)d_in[0];
  const float* Wqkv  = (const float*)d_in[1];
  const float* bqkv  = (const float*)d_in[2];
  const float* Wproj = (const float*)d_in[3];
  const float* bproj = (const float*)d_in[4];
  float* out = (float*)d_out;
  char* ws = (char*)d_ws;

  // workspace layout (160 MB total)
  unsigned short* xb     = (unsigned short*)(ws);               // 32MB  [BT][NC] bf16
  unsigned short* WqkvT  = (unsigned short*)(ws + 33554432);    // 24MB  [6144][2048]
  unsigned short* WprojT = (unsigned short*)(ws + 58720256);    // 8MB   [2048][2048]
  unsigned short* Qb     = (unsigned short*)(ws + 67108864);    // 32MB  [BH][T][D]
  unsigned short* Kb     = (unsigned short*)(ws + 100663296);   // 32MB
  unsigned short* Vb     = (unsigned short*)(ws + 134217728);   // 32MB
  unsigned short* att    = xb;  // reuse (xb dead after GEMM1)

  k_convert_bf16<<<dim3(8192), dim3(256), 0, stream>>>(x, xb, BT * NC / 8);
  k_transpose_bf16<<<dim3(96, 32), dim3(256), 0, stream>>>(Wqkv, WqkvT, NC, 3 * NC);
  k_transpose_bf16<<<dim3(32, 32), dim3(256), 0, stream>>>(Wproj, WprojT, NC, NC);
  k_gemm_bt2<0><<<dim3(48, 32), dim3(256), 0, stream>>>(xb, WqkvT, bqkv, nullptr, Qb, Kb, Vb, BT, 3 * NC, NC);
  k_rope<<<dim3(32768), dim3(256), 0, stream>>>(Qb, Kb);
  k_attn<<<dim3(64, 16), dim3(256), 0, stream>>>(Qb, Kb, Vb, att);
  k_gemm_bt2<1><<<dim3(16, 32), dim3(256), 0, stream>>>(att, WprojT, bproj, out, nullptr, nullptr, nullptr, BT, NC, NC);
}